// Round 4
// baseline (279.105 us; speedup 1.0000x reference)
//
#include <hip/hip_runtime.h>

// MultiheadAttention: B=4,S=2048,C=1024,E=1024,H=16,D=64. fp32 in/out.
// Pipeline: cvt x->f16; transpose+cvt w_qkv,w_out; QKV GEMM (f16 MFMA, fp32 acc)
// -> Q(scaled)/K [B,H,S,D], V^T [B,H,D,S]; flash attention -> ctx [tok][E];
// out-proj GEMM -> fp32 d_out. Needs 72MB workspace.
//
// R7: attn: full-rate 16x16x32 PV via key-permutation trick; 512-thr blocks.
// R8: attn: permuted-key lV (PV B-frag = one b128); XCD swizzle (bh per XCD).
// R9: GEMMs: XCD swizzle flipped (A-slice per XCD, FETCH 135->49MB); BK=64 +
// XOR-swizzled LDS (conflicts 6.3M->0). qkv still 71% stalled (2-barrier drain).
// R10: qkv -> 256^2 8-phase schedule (T2+T3+T4+T5): 8 waves (2Mx4N), BK=64,
// 128KB LDS dbuf, 4 phases/K-tile {12 ds_read_b128; stage 1 half-tile; raw
// s_barrier; 16 MFMA (setprio); s_barrier}, counted vmcnt(4) ONCE per K-tile
// (never 0 in loop). Stage schedule (derived-safe): p0:A1(t+1) p1:B1(t+1)
// p2:A0(t+2) p3:B0(t+2) -- each staged region's reads completed >=1 phase ago;
// wrap-staging keeps vmcnt uniform so the tail needs no special case.

typedef _Float16 f16;
typedef f16 f16x2 __attribute__((ext_vector_type(2)));
typedef f16 f16x4 __attribute__((ext_vector_type(4)));
typedef f16 f16x8 __attribute__((ext_vector_type(8)));
typedef float f32x4 __attribute__((ext_vector_type(4)));

typedef const __attribute__((address_space(1))) void* gas_ptr;
typedef __attribute__((address_space(3))) void* lds_ptr;

__device__ __forceinline__ void load_lds16(const void* g, void* s) {
  __builtin_amdgcn_global_load_lds((gas_ptr)g, (lds_ptr)s, 16, 0, 0);
}

__device__ __forceinline__ f32x4 mfma16(f16x8 a, f16x8 b, f32x4 c) {
  return __builtin_amdgcn_mfma_f32_16x16x32_f16(a, b, c, 0, 0, 0);
}

__device__ __forceinline__ f16x2 pk2(float a, float b) {
  return __builtin_bit_cast(f16x2, __builtin_amdgcn_cvt_pkrtz(a, b));
}

// ---------------- x: fp32 -> fp16 (8 elems/thread) ----------------
__global__ __launch_bounds__(256) void cvt_x(const float* __restrict__ in, f16* __restrict__ out) {
  int i = blockIdx.x * 256 + threadIdx.x;
  const float4* p = (const float4*)in;
  float4 a = p[2 * i], b = p[2 * i + 1];
  f16x8 o;
  o[0] = (f16)a.x; o[1] = (f16)a.y; o[2] = (f16)a.z; o[3] = (f16)a.w;
  o[4] = (f16)b.x; o[5] = (f16)b.y; o[6] = (f16)b.z; o[7] = (f16)b.w;
  *(f16x8*)(out + 8 * (long)i) = o;
}

// ------------- transpose + convert: in[R][C] f32 -> out[C][R] f16 -------------
__global__ __launch_bounds__(256) void tconv(const float* __restrict__ in, f16* __restrict__ out,
                                             int R, int C) {
  __shared__ float t[32][33];
  int c0 = blockIdx.x * 32, r0 = blockIdx.y * 32;
  int tx = threadIdx.x, ty = threadIdx.y;
#pragma unroll
  for (int j = 0; j < 4; ++j)
    t[ty + 8 * j][tx] = in[(long)(r0 + ty + 8 * j) * C + c0 + tx];
  __syncthreads();
#pragma unroll
  for (int j = 0; j < 4; ++j)
    out[(long)(c0 + ty + 8 * j) * R + r0 + tx] = (f16)t[tx][ty + 8 * j];
}

// ---------------- QKV GEMM (R10): [8192x1024] @ [1024x3072] + b ----------------
// 256x256 tile, 512 threads (8 waves = 2Mx4N), BK=64, 8-phase counted-vmcnt.
// grid (32, 12). A-half h = rows with bit6==h; B-half h = rows with bit5==h.
__global__ __launch_bounds__(512, 2) void qkv_gemm(const f16* __restrict__ A, const f16* __restrict__ BT,
                                                   const float* __restrict__ bias,
                                                   f16* __restrict__ Qs, f16* __restrict__ Kk,
                                                   f16* __restrict__ Vt) {
  __shared__ __align__(16) f16 lA[2][256 * 64];
  __shared__ __align__(16) f16 lB[2][256 * 64];
  const int K = 1024;
  int tid = threadIdx.x, w = tid >> 6, lane = tid & 63, l16 = lane & 15, quad = lane >> 4;
  int wr = w >> 2, wc = w & 3;
  // XCD swizzle: XCD x owns bx in [4x,4x+4) (A slice 2MB, L2-resident). 384%8==0.
  int id = blockIdx.y * gridDim.x + blockIdx.x;
  int xcd = id & 7, cch = id >> 3;                     // cch in [0,48)
  int bx = xcd * 4 + (cch & 3), by = cch >> 2;         // by in [0,12)
  int blockM = bx * 256, blockN = by * 256;
  int sw = l16 & 7;
  f32x4 acc[8][4] = {};

  // stage one half-tile (2 x global_load_lds, 16B/lane, wave-uniform LDS base).
  // Physical 16B-chunk pc of row r holds global chunk pc^(r&7) (T2, rule 21).
  auto stA = [&](int kt, int h) {
    f16* dst = lA[kt & 1];
    int k0 = (kt & 15) << 6;
#pragma unroll
    for (int j = 0; j < 2; ++j) {
      int br = j * 128 + h * 64 + w * 8;               // wave-uniform base row
      int r = br + (lane >> 3);
      int sc = (lane & 7) ^ (r & 7);
      load_lds16(A + (long)(blockM + r) * K + k0 + sc * 8, dst + br * 64);
    }
  };
  auto stB = [&](int kt, int h) {
    f16* dst = lB[kt & 1];
    int k0 = (kt & 15) << 6;
#pragma unroll
    for (int j = 0; j < 2; ++j) {
      int br = j * 128 + (w >> 2) * 64 + h * 32 + (w & 3) * 8;
      int r = br + (lane >> 3);
      int sc = (lane & 7) ^ (r & 7);
      load_lds16(BT + (long)(blockN + r) * K + k0 + sc * 8, dst + br * 64);
    }
  };

  // prologue: tile0 full + tile1 {A0,B0}; wait all but the last 2 half-tiles.
  stA(0, 0); stA(0, 1); stB(0, 0); stB(0, 1);
  stA(1, 0); stB(1, 0);
  asm volatile("s_waitcnt vmcnt(4)" ::: "memory");
  __builtin_amdgcn_s_barrier();

  for (int t = 0; t < 16; ++t) {
    const f16* cA = lA[t & 1];
    const f16* cB = lB[t & 1];
#pragma unroll
    for (int p = 0; p < 4; ++p) {
      const int mh = p >> 1, nh = p & 1;               // C-quadrant of this phase
      f16x8 af[4][2], bf[2][2];
#pragma unroll
      for (int mf = 0; mf < 4; ++mf) {
        int rowA = wr * 128 + (mh * 4 + mf) * 16 + l16;
#pragma unroll
        for (int kk = 0; kk < 2; ++kk)
          af[mf][kk] = *(const f16x8*)&cA[rowA * 64 + ((kk * 4 + quad) ^ sw) * 8];
      }
#pragma unroll
      for (int nf = 0; nf < 2; ++nf) {
        int rowB = wc * 64 + (nh * 2 + nf) * 16 + l16;
#pragma unroll
        for (int kk = 0; kk < 2; ++kk)
          bf[nf][kk] = *(const f16x8*)&cB[rowB * 64 + ((kk * 4 + quad) ^ sw) * 8];
      }
      // stage: region's readers finished >=1 phase ago (A1 read p2,p3; B1 p1,p3;
      // A0 p0,p1; B0 p0,p2). t+1 targets the idle buffer; t+2 the current one.
      if (p == 0) stA(t + 1, 1);
      else if (p == 1) stB(t + 1, 1);
      else if (p == 2) stA(t + 2, 0);
      else stB(t + 2, 0);
      __builtin_amdgcn_s_barrier();
      __builtin_amdgcn_s_setprio(1);
#pragma unroll
      for (int mf = 0; mf < 4; ++mf)
#pragma unroll
        for (int nf = 0; nf < 2; ++nf)
#pragma unroll
          for (int kk = 0; kk < 2; ++kk)
            acc[mh * 4 + mf][nh * 2 + nf] =
                mfma16(af[mf][kk], bf[nf][kk], acc[mh * 4 + mf][nh * 2 + nf]);
      __builtin_amdgcn_s_setprio(0);
      // K-tile boundary: everything for tile t+1 must have landed; the only
      // allowed outstanding loads are tile t+2's {A0,B0} = 4.
      if (p == 3) asm volatile("s_waitcnt vmcnt(4)" ::: "memory");
      __builtin_amdgcn_s_barrier();
    }
  }

  int which = by >> 2;                           // 0=Q,1=K,2=V (block-uniform)
  const float SCALE = 0.18033688011112042f;      // log2(e)/sqrt(D)
#pragma unroll
  for (int nf = 0; nf < 4; ++nf) {
    int col = blockN + wc * 64 + nf * 16 + l16;
    int hd = col & 1023, h = hd >> 6, d = hd & 63;
    float bv = bias[col];
#pragma unroll
    for (int mf = 0; mf < 8; ++mf) {
      int row0 = blockM + wr * 128 + mf * 16 + quad * 4;   // 4 consecutive tokens
      int b = row0 >> 11, s0 = row0 & 2047;
      if (which == 2) {
        f16x2 a = pk2(acc[mf][nf][0] + bv, acc[mf][nf][1] + bv);
        f16x2 c = pk2(acc[mf][nf][2] + bv, acc[mf][nf][3] + bv);
        *(f16x4*)&Vt[((b * 16 + h) * 64 + d) * 2048 + s0] =
            __builtin_shufflevector(a, c, 0, 1, 2, 3);
      } else if (which == 0) {
#pragma unroll
        for (int r = 0; r < 4; ++r)
          Qs[((b * 16 + h) * 2048 + s0 + r) * 64 + d] = (f16)((acc[mf][nf][r] + bv) * SCALE);
      } else {
#pragma unroll
        for (int r = 0; r < 4; ++r)
          Kk[((b * 16 + h) * 2048 + s0 + r) * 64 + d] = (f16)(acc[mf][nf][r] + bv);
      }
    }
  }
}

// ---------------- Flash attention (R8) ----------------
// grid (8,64) -> XCD-swizzled to (qt, bh) so each XCD owns 8 bh (K/V L2-hot).
// 512 threads = 8 waves; wave owns 32 Q rows. Key tile 64 = 2 kp-groups of 32.
// Q pre-scaled -> exp2 domain; no online max (scores bounded).
// S^T = K*Q^T (16x16x32); P stays in registers (C-layout -> A-frag by reg
// concat under a key permutation applied identically to V).
// lV stores key 16h+4q+j of each kp-group at column 8q+4h+j, so the PV B-frag
// is ONE ds_read_b128 (stride-144 balanced banks). Row-sum via ones-B MFMA.
// lK/lV dbuf, reg prefetch, 1 barrier/kt, setprio around MFMA cluster.
__global__ __launch_bounds__(512, 4) void attn(const f16* __restrict__ Qs, const f16* __restrict__ Kk,
                                               const f16* __restrict__ Vt, f16* __restrict__ ctx) {
  __shared__ __align__(16) f16 lK[2][64 * 72];   // [key][d], stride 72
  __shared__ __align__(16) f16 lV[2][64 * 72];   // [d][permuted key]
  int id = blockIdx.y * gridDim.x + blockIdx.x;        // 512 blocks
  int swz = (id & 7) * 64 + (id >> 3);
  int qt = swz & 7, bh = swz >> 3;
  int tid = threadIdx.x, lane = tid & 63, l16 = lane & 15, quad = lane >> 4;
  int w = tid >> 6;                               // 8 waves
  const f16* Qbase = Qs + ((long)bh * 2048 + qt * 256 + w * 32) * 64;
  const f16* Kbh = Kk + (long)bh * 2048 * 64;
  const f16* Vbh = Vt + (long)bh * 64 * 2048;

  f16x8 qf[2][2];                                // B-frag: [n=row=rb*16+l16][k=d]
#pragma unroll
  for (int rb = 0; rb < 2; ++rb)
#pragma unroll
    for (int ks = 0; ks < 2; ++ks)
      qf[rb][ks] = *(const f16x8*)(Qbase + (rb * 16 + l16) * 64 + ks * 32 + quad * 8);

  f32x4 of[2][4] = {};
  f32x4 osum[2] = {};
  const f16 one = (f16)1.f;
  const f16x8 vone8 = {one, one, one, one, one, one, one, one};

  int rs = tid >> 3, o = (tid & 7) * 8;
  int koff = o & 31;
  int cperm = (o & 32) + ((koff & 12) << 1) + ((koff >> 4) << 2);  // kp*32+8qa+4h

  {
    *(float4*)&lK[0][rs * 72 + o] = *(const float4*)(Kbh + rs * 64 + o);
    float4 pv = *(const float4*)(Vbh + (long)rs * 2048 + o);
    f16x8 v8 = __builtin_bit_cast(f16x8, pv);
    *(f16x4*)&lV[0][rs * 72 + cperm] = __builtin_shufflevector(v8, v8, 0, 1, 2, 3);
    *(f16x4*)&lV[0][rs * 72 + cperm + 8] = __builtin_shufflevector(v8, v8, 4, 5, 6, 7);
  }
  __syncthreads();

  for (int kt = 0; kt < 32; ++kt) {
    int cur = kt & 1, nxt = cur ^ 1;

    float4 pk0, pv0;
    if (kt < 31) {
      int kb0 = (kt + 1) * 64;
      pk0 = *(const float4*)(Kbh + (kb0 + rs) * 64 + o);
      pv0 = *(const float4*)(Vbh + (long)rs * 2048 + kb0 + o);
    }

    __builtin_amdgcn_s_setprio(1);
#pragma unroll
    for (int kp = 0; kp < 2; ++kp) {             // 32-key pair
      f16x4 pah[2][2];                           // [rb][kbh]: packed exp, keys 4q..4q+3
#pragma unroll
      for (int kbh = 0; kbh < 2; ++kbh) {
        int kb = kp * 2 + kbh;
        f16x8 kf0 = *(const f16x8*)&lK[cur][(kb * 16 + l16) * 72 + quad * 8];
        f16x8 kf1 = *(const f16x8*)&lK[cur][(kb * 16 + l16) * 72 + 32 + quad * 8];
#pragma unroll
        for (int rb = 0; rb < 2; ++rb) {
          f32x4 z = {};
          z = mfma16(kf0, qf[rb][0], z);
          z = mfma16(kf1, qf[rb][1], z);
          float p0 = __builtin_amdgcn_exp2f(z[0]);
          float p1 = __builtin_amdgcn_exp2f(z[1]);
          float p2 = __builtin_amdgcn_exp2f(z[2]);
          float p3 = __builtin_amdgcn_exp2f(z[3]);
          pah[rb][kbh] = __builtin_shufflevector(pk2(p0, p1), pk2(p2, p3), 0, 1, 2, 3);
        }
      }
      f16x8 pa[2];
      pa[0] = __builtin_shufflevector(pah[0][0], pah[0][1], 0, 1, 2, 3, 4, 5, 6, 7);
      pa[1] = __builtin_shufflevector(pah[1][0], pah[1][1], 0, 1, 2, 3, 4, 5, 6, 7);

#pragma unroll
      for (int db = 0; db < 4; ++db) {
        f16x8 vf = *(const f16x8*)&lV[cur][(db * 16 + l16) * 72 + kp * 32 + quad * 8];
#pragma unroll
        for (int rb = 0; rb < 2; ++rb)
          of[rb][db] = mfma16(pa[rb], vf, of[rb][db]);
      }
#pragma unroll
      for (int rb = 0; rb < 2; ++rb)
        osum[rb] = mfma16(pa[rb], vone8, osum[rb]);
    }
    __builtin_amdgcn_s_setprio(0);

    if (kt < 31) {
      *(float4*)&lK[nxt][rs * 72 + o] = pk0;
      f16x8 v8 = __builtin_bit_cast(f16x8, pv0);
      *(f16x4*)&lV[nxt][rs * 72 + cperm] = __builtin_shufflevector(v8, v8, 0, 1, 2, 3);
      *(f16x4*)&lV[nxt][rs * 72 + cperm + 8] = __builtin_shufflevector(v8, v8, 4, 5, 6, 7);
      __syncthreads();
    }
  }

  int b = bh >> 4, h = bh & 15;
  long token0 = (long)b * 2048 + qt * 256 + w * 32;
#pragma unroll
  for (int rb = 0; rb < 2; ++rb) {
    float inv[4];
#pragma unroll
    for (int r = 0; r < 4; ++r) inv[r] = 1.0f / osum[rb][r];   // in-lane: same C-layout
#pragma unroll
    for (int db = 0; db < 4; ++db)
#pragma unroll
      for (int r = 0; r < 4; ++r)
        ctx[(token0 + rb * 16 + quad * 4 + r) * 1024 + h * 64 + db * 16 + l16] =
            (f16)(of[rb][db][r] * inv[r]);
  }
}

// ---------------- out-proj GEMM: [8192x1024] @ [1024x1024] + b -> fp32 ----------------
__global__ __launch_bounds__(256) void proj_gemm(const f16* __restrict__ A, const f16* __restrict__ BT,
                                                 const float* __restrict__ bias,
                                                 float* __restrict__ out) {
  __shared__ __align__(16) f16 lA[128 * 64];
  __shared__ __align__(16) f16 lB[128 * 64];
  const int K = 1024;
  int tid = threadIdx.x, w = tid >> 6, lane = tid & 63, l16 = lane & 15, quad = lane >> 4;
  int wm = (w >> 1) * 64, wn = (w & 1) * 64;
  // XCD swizzle: XCD x owns blockM rows [8x,8x+8); A and B slices both L2-fit.
  int id = blockIdx.y * gridDim.x + blockIdx.x;        // 512 blocks
  int xcd = id & 7, cch = id >> 3;                     // cch in [0,64)
  int bx = xcd * 8 + (cch & 7), by = cch >> 3;         // by in [0,8)
  int blockM = bx * 128, blockN = by * 128;
  int sw = l16 & 7;
  f32x4 acc[4][4] = {};

  for (int k0 = 0; k0 < K; k0 += 64) {
    __syncthreads();
#pragma unroll
    for (int i = 0; i < 4; ++i) {
      int c = i * 256 + tid;
      int row = c >> 3;
      int sc = (c & 7) ^ (row & 7);
      load_lds16(A + (blockM + row) * K + k0 + sc * 8, lA + c * 8);
      load_lds16(BT + (blockN + row) * K + k0 + sc * 8, lB + c * 8);
    }
    __syncthreads();
#pragma unroll
    for (int ks = 0; ks < 2; ++ks) {
      f16x8 af[4], bf[4];
#pragma unroll
      for (int mb = 0; mb < 4; ++mb)
        af[mb] = *(const f16x8*)&lA[(wm + mb * 16 + l16) * 64 + ((ks * 4 + quad) ^ sw) * 8];
#pragma unroll
      for (int nb = 0; nb < 4; ++nb)
        bf[nb] = *(const f16x8*)&lB[(wn + nb * 16 + l16) * 64 + ((ks * 4 + quad) ^ sw) * 8];
#pragma unroll
      for (int mb = 0; mb < 4; ++mb)
#pragma unroll
        for (int nb = 0; nb < 4; ++nb)
          acc[mb][nb] = mfma16(af[mb], bf[nb], acc[mb][nb]);
    }
  }

#pragma unroll
  for (int nb = 0; nb < 4; ++nb) {
    int col = blockN + wn + nb * 16 + l16;
    float bv = bias[col];
#pragma unroll
    for (int mb = 0; mb < 4; ++mb) {
#pragma unroll
      for (int r = 0; r < 4; ++r) {
        int row = blockM + wm + mb * 16 + quad * 4 + r;
        out[(long)row * 1024 + col] = acc[mb][nb][r] + bv;
      }
    }
  }
}

extern "C" void kernel_launch(void* const* d_in, const int* in_sizes, int n_in,
                              void* d_out, int out_size, void* d_ws, size_t ws_size,
                              hipStream_t stream) {
  const float* x     = (const float*)d_in[0];
  const float* w_qkv = (const float*)d_in[1];
  const float* b_qkv = (const float*)d_in[2];
  const float* w_out = (const float*)d_in[3];
  const float* b_out = (const float*)d_in[4];
  float* out = (float*)d_out;

  char* ws = (char*)d_ws;
  f16* xh    = (f16*)(ws);                        // 16,777,216  [8192][1024]
  f16* ctx   = (f16*)(ws);                        // aliased (xh dead after qkv_gemm)
  f16* wqkvT = (f16*)(ws + 16777216);             //  6,291,456  [3072][1024]
  f16* woutT = (f16*)(ws + 23068672);             //  2,097,152  [1024][1024]
  f16* Qs    = (f16*)(ws + 25165824);             // 16,777,216  [64][2048][64] scaled
  f16* Kk    = (f16*)(ws + 41943040);             // 16,777,216  [64][2048][64]
  f16* Vt    = (f16*)(ws + 58720256);             // 16,777,216  [64][64][2048]

  cvt_x<<<4096, 256, 0, stream>>>(x, xh);
  tconv<<<dim3(96, 32), dim3(32, 8), 0, stream>>>(w_qkv, wqkvT, 1024, 3072);
  tconv<<<dim3(32, 32), dim3(32, 8), 0, stream>>>(w_out, woutT, 1024, 1024);
  qkv_gemm<<<dim3(32, 12), 512, 0, stream>>>(xh, wqkvT, b_qkv, Qs, Kk, Vt);
  attn<<<dim3(8, 64), 512, 0, stream>>>(Qs, Kk, Vt, ctx);
  proj_gemm<<<dim3(64, 8), 256, 0, stream>>>(ctx, woutT, b_out, out);
}

// Round 5
// 262.805 us; speedup vs baseline: 1.0620x; 1.0620x over previous
//
#include <hip/hip_runtime.h>

// MultiheadAttention: B=4,S=2048,C=1024,E=1024,H=16,D=64. fp32 in/out.
// Pipeline: cvt x->f16; transpose+cvt w_qkv,w_out; QKV GEMM (f16 MFMA, fp32 acc)
// -> Q(scaled)/K [B,H,S,D], V^T [B,H,D,S]; flash attention -> ctx [tok][E];
// out-proj GEMM -> fp32 d_out. Needs 72MB workspace.
//
// R7: attn: full-rate 16x16x32 PV via key-permutation trick; 512-thr blocks.
// R8: attn: permuted-key lV (PV B-frag = one b128); XCD swizzle (bh per XCD).
// R9: GEMMs: XCD swizzle flipped (A-slice per XCD); BK=64 + XOR-swizzled LDS.
// R10: qkv -> 256^2 8-wave 4-phase dbuf schedule. REGRESSED (100us): phases
// re-read af+bf per C-quadrant (48 b128/K-tile vs 24 min) -> LDS-read-bound.
// R11: read each fragment ONCE per K-tile, hold in regs across phases:
// p0 {af(mh0)8 + bf 8 reads; stage A1(t+1); bar; MFMA (0,0); bar}
// p1 {stage B1(t+1); bar; MFMA (0,1); bar}
// p2 {af(mh1)8 reads; stage A0(t+2); bar; MFMA (1,0); bar}
// p3 {stage B0(t+2); bar; MFMA (1,1); vmcnt(4); bar}
// Stage legality: each staged region's readers finished >=1 barrier earlier
// (A1(t+1): read t-1 p2; B1(t+1): read t-1 p0, used p1/p3; A0(t+2): read p0,
// used p0/p1; B0(t+2): read p0, used p0/p2). No wrap-staging: guards at t>=14,
// vmcnt(0) once at the t=14 boundary (saves 24MB junk refetch).

typedef _Float16 f16;
typedef f16 f16x2 __attribute__((ext_vector_type(2)));
typedef f16 f16x4 __attribute__((ext_vector_type(4)));
typedef f16 f16x8 __attribute__((ext_vector_type(8)));
typedef float f32x4 __attribute__((ext_vector_type(4)));

typedef const __attribute__((address_space(1))) void* gas_ptr;
typedef __attribute__((address_space(3))) void* lds_ptr;

__device__ __forceinline__ void load_lds16(const void* g, void* s) {
  __builtin_amdgcn_global_load_lds((gas_ptr)g, (lds_ptr)s, 16, 0, 0);
}

__device__ __forceinline__ f32x4 mfma16(f16x8 a, f16x8 b, f32x4 c) {
  return __builtin_amdgcn_mfma_f32_16x16x32_f16(a, b, c, 0, 0, 0);
}

__device__ __forceinline__ f16x2 pk2(float a, float b) {
  return __builtin_bit_cast(f16x2, __builtin_amdgcn_cvt_pkrtz(a, b));
}

// ---------------- x: fp32 -> fp16 (8 elems/thread) ----------------
__global__ __launch_bounds__(256) void cvt_x(const float* __restrict__ in, f16* __restrict__ out) {
  int i = blockIdx.x * 256 + threadIdx.x;
  const float4* p = (const float4*)in;
  float4 a = p[2 * i], b = p[2 * i + 1];
  f16x8 o;
  o[0] = (f16)a.x; o[1] = (f16)a.y; o[2] = (f16)a.z; o[3] = (f16)a.w;
  o[4] = (f16)b.x; o[5] = (f16)b.y; o[6] = (f16)b.z; o[7] = (f16)b.w;
  *(f16x8*)(out + 8 * (long)i) = o;
}

// ------------- transpose + convert: in[R][C] f32 -> out[C][R] f16 -------------
__global__ __launch_bounds__(256) void tconv(const float* __restrict__ in, f16* __restrict__ out,
                                             int R, int C) {
  __shared__ float t[32][33];
  int c0 = blockIdx.x * 32, r0 = blockIdx.y * 32;
  int tx = threadIdx.x, ty = threadIdx.y;
#pragma unroll
  for (int j = 0; j < 4; ++j)
    t[ty + 8 * j][tx] = in[(long)(r0 + ty + 8 * j) * C + c0 + tx];
  __syncthreads();
#pragma unroll
  for (int j = 0; j < 4; ++j)
    out[(long)(c0 + ty + 8 * j) * R + r0 + tx] = (f16)t[tx][ty + 8 * j];
}

// ---------------- QKV GEMM (R11): [8192x1024] @ [1024x3072] + b ----------------
// 256x256 tile, 512 threads (8 waves = 2Mx4N), BK=64, 4-phase counted-vmcnt,
// fragments read once per K-tile and held in regs. grid (32, 12).
__global__ __launch_bounds__(512, 2) void qkv_gemm(const f16* __restrict__ A, const f16* __restrict__ BT,
                                                   const float* __restrict__ bias,
                                                   f16* __restrict__ Qs, f16* __restrict__ Kk,
                                                   f16* __restrict__ Vt) {
  __shared__ __align__(16) f16 lA[2][256 * 64];
  __shared__ __align__(16) f16 lB[2][256 * 64];
  const int K = 1024;
  int tid = threadIdx.x, w = tid >> 6, lane = tid & 63, l16 = lane & 15, quad = lane >> 4;
  int wr = w >> 2, wc = w & 3;
  // XCD swizzle: XCD x owns bx in [4x,4x+4) (A slice 2MB, L2-resident). 384%8==0.
  int id = blockIdx.y * gridDim.x + blockIdx.x;
  int xcd = id & 7, cch = id >> 3;                     // cch in [0,48)
  int bx = xcd * 4 + (cch & 3), by = cch >> 2;         // by in [0,12)
  int blockM = bx * 256, blockN = by * 256;
  int sw = l16 & 7;
  f32x4 acc[8][4] = {};

  // stage one half-tile (2 x global_load_lds, 16B/lane, wave-uniform LDS base).
  // Physical 16B-chunk pc of row r holds global chunk pc^(r&7) (T2, rule 21).
  // A-half h = rows with bit6==h; B-half h = rows with bit5==h.
  auto stA = [&](int kt, int h) {
    f16* dst = lA[kt & 1];
    int k0 = kt << 6;
#pragma unroll
    for (int j = 0; j < 2; ++j) {
      int br = j * 128 + h * 64 + w * 8;               // wave-uniform base row
      int r = br + (lane >> 3);
      int sc = (lane & 7) ^ (r & 7);
      load_lds16(A + (long)(blockM + r) * K + k0 + sc * 8, dst + br * 64);
    }
  };
  auto stB = [&](int kt, int h) {
    f16* dst = lB[kt & 1];
    int k0 = kt << 6;
#pragma unroll
    for (int j = 0; j < 2; ++j) {
      int br = j * 128 + (w >> 2) * 64 + h * 32 + (w & 3) * 8;
      int r = br + (lane >> 3);
      int sc = (lane & 7) ^ (r & 7);
      load_lds16(BT + (long)(blockN + r) * K + k0 + sc * 8, dst + br * 64);
    }
  };

  // prologue: tile0 full + tile1 {A0,B0}; wait all but the last 2 half-tiles.
  stA(0, 0); stA(0, 1); stB(0, 0); stB(0, 1);
  stA(1, 0); stB(1, 0);
  asm volatile("s_waitcnt vmcnt(4)" ::: "memory");
  __builtin_amdgcn_s_barrier();

  for (int t = 0; t < 16; ++t) {
    const f16* cA = lA[t & 1];
    const f16* cB = lB[t & 1];
    f16x8 af[4][2], bf[4][2];

    // ---- p0: read af(mh0) + all bf; stage A1(t+1); MFMA quadrant (0,0) ----
#pragma unroll
    for (int mf = 0; mf < 4; ++mf) {
      int rowA = wr * 128 + mf * 16 + l16;
#pragma unroll
      for (int kk = 0; kk < 2; ++kk)
        af[mf][kk] = *(const f16x8*)&cA[rowA * 64 + ((kk * 4 + quad) ^ sw) * 8];
    }
#pragma unroll
    for (int nf = 0; nf < 4; ++nf) {
      int rowB = wc * 64 + nf * 16 + l16;
#pragma unroll
      for (int kk = 0; kk < 2; ++kk)
        bf[nf][kk] = *(const f16x8*)&cB[rowB * 64 + ((kk * 4 + quad) ^ sw) * 8];
    }
    if (t < 15) stA(t + 1, 1);
    __builtin_amdgcn_s_barrier();
    __builtin_amdgcn_s_setprio(1);
#pragma unroll
    for (int mf = 0; mf < 4; ++mf)
#pragma unroll
      for (int nf = 0; nf < 2; ++nf)
#pragma unroll
        for (int kk = 0; kk < 2; ++kk)
          acc[mf][nf] = mfma16(af[mf][kk], bf[nf][kk], acc[mf][nf]);
    __builtin_amdgcn_s_setprio(0);
    __builtin_amdgcn_s_barrier();

    // ---- p1: stage B1(t+1); MFMA quadrant (0,1) ----
    if (t < 15) stB(t + 1, 1);
    __builtin_amdgcn_s_barrier();
    __builtin_amdgcn_s_setprio(1);
#pragma unroll
    for (int mf = 0; mf < 4; ++mf)
#pragma unroll
      for (int nf = 0; nf < 2; ++nf)
#pragma unroll
        for (int kk = 0; kk < 2; ++kk)
          acc[mf][2 + nf] = mfma16(af[mf][kk], bf[2 + nf][kk], acc[mf][2 + nf]);
    __builtin_amdgcn_s_setprio(0);
    __builtin_amdgcn_s_barrier();

    // ---- p2: read af(mh1) (overwrites held af); stage A0(t+2); MFMA (1,0) ----
#pragma unroll
    for (int mf = 0; mf < 4; ++mf) {
      int rowA = wr * 128 + 64 + mf * 16 + l16;
#pragma unroll
      for (int kk = 0; kk < 2; ++kk)
        af[mf][kk] = *(const f16x8*)&cA[rowA * 64 + ((kk * 4 + quad) ^ sw) * 8];
    }
    if (t < 14) stA(t + 2, 0);
    __builtin_amdgcn_s_barrier();
    __builtin_amdgcn_s_setprio(1);
#pragma unroll
    for (int mf = 0; mf < 4; ++mf)
#pragma unroll
      for (int nf = 0; nf < 2; ++nf)
#pragma unroll
        for (int kk = 0; kk < 2; ++kk)
          acc[4 + mf][nf] = mfma16(af[mf][kk], bf[nf][kk], acc[4 + mf][nf]);
    __builtin_amdgcn_s_setprio(0);
    __builtin_amdgcn_s_barrier();

    // ---- p3: stage B0(t+2); MFMA (1,1); K-tile boundary wait ----
    if (t < 14) stB(t + 2, 0);
    __builtin_amdgcn_s_barrier();
    __builtin_amdgcn_s_setprio(1);
#pragma unroll
    for (int mf = 0; mf < 4; ++mf)
#pragma unroll
      for (int nf = 0; nf < 2; ++nf)
#pragma unroll
        for (int kk = 0; kk < 2; ++kk)
          acc[4 + mf][2 + nf] = mfma16(af[mf][kk], bf[2 + nf][kk], acc[4 + mf][2 + nf]);
    __builtin_amdgcn_s_setprio(0);
    // tile t+1 must have fully landed; the only allowed outstanding loads are
    // tile t+2's {A0,B0} = 4. At t=14 nothing further is staged -> drain.
    if (t < 14) asm volatile("s_waitcnt vmcnt(4)" ::: "memory");
    else if (t == 14) asm volatile("s_waitcnt vmcnt(0)" ::: "memory");
    __builtin_amdgcn_s_barrier();
  }

  int which = by >> 2;                           // 0=Q,1=K,2=V (block-uniform)
  const float SCALE = 0.18033688011112042f;      // log2(e)/sqrt(D)
#pragma unroll
  for (int nf = 0; nf < 4; ++nf) {
    int col = blockN + wc * 64 + nf * 16 + l16;
    int hd = col & 1023, h = hd >> 6, d = hd & 63;
    float bv = bias[col];
#pragma unroll
    for (int mf = 0; mf < 8; ++mf) {
      int row0 = blockM + wr * 128 + mf * 16 + quad * 4;   // 4 consecutive tokens
      int b = row0 >> 11, s0 = row0 & 2047;
      if (which == 2) {
        f16x2 a = pk2(acc[mf][nf][0] + bv, acc[mf][nf][1] + bv);
        f16x2 c = pk2(acc[mf][nf][2] + bv, acc[mf][nf][3] + bv);
        *(f16x4*)&Vt[((b * 16 + h) * 64 + d) * 2048 + s0] =
            __builtin_shufflevector(a, c, 0, 1, 2, 3);
      } else if (which == 0) {
#pragma unroll
        for (int r = 0; r < 4; ++r)
          Qs[((b * 16 + h) * 2048 + s0 + r) * 64 + d] = (f16)((acc[mf][nf][r] + bv) * SCALE);
      } else {
#pragma unroll
        for (int r = 0; r < 4; ++r)
          Kk[((b * 16 + h) * 2048 + s0 + r) * 64 + d] = (f16)(acc[mf][nf][r] + bv);
      }
    }
  }
}

// ---------------- Flash attention (R8) ----------------
// grid (8,64) -> XCD-swizzled to (qt, bh) so each XCD owns 8 bh (K/V L2-hot).
// 512 threads = 8 waves; wave owns 32 Q rows. Key tile 64 = 2 kp-groups of 32.
// Q pre-scaled -> exp2 domain; no online max (scores bounded).
// S^T = K*Q^T (16x16x32); P stays in registers (C-layout -> A-frag by reg
// concat under a key permutation applied identically to V).
// lV stores key 16h+4q+j of each kp-group at column 8q+4h+j, so the PV B-frag
// is ONE ds_read_b128 (stride-144 balanced banks). Row-sum via ones-B MFMA.
// lK/lV dbuf, reg prefetch, 1 barrier/kt, setprio around MFMA cluster.
__global__ __launch_bounds__(512, 4) void attn(const f16* __restrict__ Qs, const f16* __restrict__ Kk,
                                               const f16* __restrict__ Vt, f16* __restrict__ ctx) {
  __shared__ __align__(16) f16 lK[2][64 * 72];   // [key][d], stride 72
  __shared__ __align__(16) f16 lV[2][64 * 72];   // [d][permuted key]
  int id = blockIdx.y * gridDim.x + blockIdx.x;        // 512 blocks
  int swz = (id & 7) * 64 + (id >> 3);
  int qt = swz & 7, bh = swz >> 3;
  int tid = threadIdx.x, lane = tid & 63, l16 = lane & 15, quad = lane >> 4;
  int w = tid >> 6;                               // 8 waves
  const f16* Qbase = Qs + ((long)bh * 2048 + qt * 256 + w * 32) * 64;
  const f16* Kbh = Kk + (long)bh * 2048 * 64;
  const f16* Vbh = Vt + (long)bh * 64 * 2048;

  f16x8 qf[2][2];                                // B-frag: [n=row=rb*16+l16][k=d]
#pragma unroll
  for (int rb = 0; rb < 2; ++rb)
#pragma unroll
    for (int ks = 0; ks < 2; ++ks)
      qf[rb][ks] = *(const f16x8*)(Qbase + (rb * 16 + l16) * 64 + ks * 32 + quad * 8);

  f32x4 of[2][4] = {};
  f32x4 osum[2] = {};
  const f16 one = (f16)1.f;
  const f16x8 vone8 = {one, one, one, one, one, one, one, one};

  int rs = tid >> 3, o = (tid & 7) * 8;
  int koff = o & 31;
  int cperm = (o & 32) + ((koff & 12) << 1) + ((koff >> 4) << 2);  // kp*32+8qa+4h

  {
    *(float4*)&lK[0][rs * 72 + o] = *(const float4*)(Kbh + rs * 64 + o);
    float4 pv = *(const float4*)(Vbh + (long)rs * 2048 + o);
    f16x8 v8 = __builtin_bit_cast(f16x8, pv);
    *(f16x4*)&lV[0][rs * 72 + cperm] = __builtin_shufflevector(v8, v8, 0, 1, 2, 3);
    *(f16x4*)&lV[0][rs * 72 + cperm + 8] = __builtin_shufflevector(v8, v8, 4, 5, 6, 7);
  }
  __syncthreads();

  for (int kt = 0; kt < 32; ++kt) {
    int cur = kt & 1, nxt = cur ^ 1;

    float4 pk0, pv0;
    if (kt < 31) {
      int kb0 = (kt + 1) * 64;
      pk0 = *(const float4*)(Kbh + (kb0 + rs) * 64 + o);
      pv0 = *(const float4*)(Vbh + (long)rs * 2048 + kb0 + o);
    }

    __builtin_amdgcn_s_setprio(1);
#pragma unroll
    for (int kp = 0; kp < 2; ++kp) {             // 32-key pair
      f16x4 pah[2][2];                           // [rb][kbh]: packed exp, keys 4q..4q+3
#pragma unroll
      for (int kbh = 0; kbh < 2; ++kbh) {
        int kb = kp * 2 + kbh;
        f16x8 kf0 = *(const f16x8*)&lK[cur][(kb * 16 + l16) * 72 + quad * 8];
        f16x8 kf1 = *(const f16x8*)&lK[cur][(kb * 16 + l16) * 72 + 32 + quad * 8];
#pragma unroll
        for (int rb = 0; rb < 2; ++rb) {
          f32x4 z = {};
          z = mfma16(kf0, qf[rb][0], z);
          z = mfma16(kf1, qf[rb][1], z);
          float p0 = __builtin_amdgcn_exp2f(z[0]);
          float p1 = __builtin_amdgcn_exp2f(z[1]);
          float p2 = __builtin_amdgcn_exp2f(z[2]);
          float p3 = __builtin_amdgcn_exp2f(z[3]);
          pah[rb][kbh] = __builtin_shufflevector(pk2(p0, p1), pk2(p2, p3), 0, 1, 2, 3);
        }
      }
      f16x8 pa[2];
      pa[0] = __builtin_shufflevector(pah[0][0], pah[0][1], 0, 1, 2, 3, 4, 5, 6, 7);
      pa[1] = __builtin_shufflevector(pah[1][0], pah[1][1], 0, 1, 2, 3, 4, 5, 6, 7);

#pragma unroll
      for (int db = 0; db < 4; ++db) {
        f16x8 vf = *(const f16x8*)&lV[cur][(db * 16 + l16) * 72 + kp * 32 + quad * 8];
#pragma unroll
        for (int rb = 0; rb < 2; ++rb)
          of[rb][db] = mfma16(pa[rb], vf, of[rb][db]);
      }
#pragma unroll
      for (int rb = 0; rb < 2; ++rb)
        osum[rb] = mfma16(pa[rb], vone8, osum[rb]);
    }
    __builtin_amdgcn_s_setprio(0);

    if (kt < 31) {
      *(float4*)&lK[nxt][rs * 72 + o] = pk0;
      f16x8 v8 = __builtin_bit_cast(f16x8, pv0);
      *(f16x4*)&lV[nxt][rs * 72 + cperm] = __builtin_shufflevector(v8, v8, 0, 1, 2, 3);
      *(f16x4*)&lV[nxt][rs * 72 + cperm + 8] = __builtin_shufflevector(v8, v8, 4, 5, 6, 7);
      __syncthreads();
    }
  }

  int b = bh >> 4, h = bh & 15;
  long token0 = (long)b * 2048 + qt * 256 + w * 32;
#pragma unroll
  for (int rb = 0; rb < 2; ++rb) {
    float inv[4];
#pragma unroll
    for (int r = 0; r < 4; ++r) inv[r] = 1.0f / osum[rb][r];   // in-lane: same C-layout
#pragma unroll
    for (int db = 0; db < 4; ++db)
#pragma unroll
      for (int r = 0; r < 4; ++r)
        ctx[(token0 + rb * 16 + quad * 4 + r) * 1024 + h * 64 + db * 16 + l16] =
            (f16)(of[rb][db][r] * inv[r]);
  }
}

// ---------------- out-proj GEMM: [8192x1024] @ [1024x1024] + b -> fp32 ----------------
__global__ __launch_bounds__(256) void proj_gemm(const f16* __restrict__ A, const f16* __restrict__ BT,
                                                 const float* __restrict__ bias,
                                                 float* __restrict__ out) {
  __shared__ __align__(16) f16 lA[128 * 64];
  __shared__ __align__(16) f16 lB[128 * 64];
  const int K = 1024;
  int tid = threadIdx.x, w = tid >> 6, lane = tid & 63, l16 = lane & 15, quad = lane >> 4;
  int wm = (w >> 1) * 64, wn = (w & 1) * 64;
  // XCD swizzle: XCD x owns blockM rows [8x,8x+8); A and B slices both L2-fit.
  int id = blockIdx.y * gridDim.x + blockIdx.x;        // 512 blocks
  int xcd = id & 7, cch = id >> 3;                     // cch in [0,64)
  int bx = xcd * 8 + (cch & 7), by = cch >> 3;         // by in [0,8)
  int blockM = bx * 128, blockN = by * 128;
  int sw = l16 & 7;
  f32x4 acc[4][4] = {};

  for (int k0 = 0; k0 < K; k0 += 64) {
    __syncthreads();
#pragma unroll
    for (int i = 0; i < 4; ++i) {
      int c = i * 256 + tid;
      int row = c >> 3;
      int sc = (c & 7) ^ (row & 7);
      load_lds16(A + (blockM + row) * K + k0 + sc * 8, lA + c * 8);
      load_lds16(BT + (blockN + row) * K + k0 + sc * 8, lB + c * 8);
    }
    __syncthreads();
#pragma unroll
    for (int ks = 0; ks < 2; ++ks) {
      f16x8 af[4], bf[4];
#pragma unroll
      for (int mb = 0; mb < 4; ++mb)
        af[mb] = *(const f16x8*)&lA[(wm + mb * 16 + l16) * 64 + ((ks * 4 + quad) ^ sw) * 8];
#pragma unroll
      for (int nb = 0; nb < 4; ++nb)
        bf[nb] = *(const f16x8*)&lB[(wn + nb * 16 + l16) * 64 + ((ks * 4 + quad) ^ sw) * 8];
#pragma unroll
      for (int mb = 0; mb < 4; ++mb)
#pragma unroll
        for (int nb = 0; nb < 4; ++nb)
          acc[mb][nb] = mfma16(af[mb], bf[nb], acc[mb][nb]);
    }
  }

#pragma unroll
  for (int nb = 0; nb < 4; ++nb) {
    int col = blockN + wn + nb * 16 + l16;
    float bv = bias[col];
#pragma unroll
    for (int mb = 0; mb < 4; ++mb) {
#pragma unroll
      for (int r = 0; r < 4; ++r) {
        int row = blockM + wm + mb * 16 + quad * 4 + r;
        out[(long)row * 1024 + col] = acc[mb][nb][r] + bv;
      }
    }
  }
}

extern "C" void kernel_launch(void* const* d_in, const int* in_sizes, int n_in,
                              void* d_out, int out_size, void* d_ws, size_t ws_size,
                              hipStream_t stream) {
  const float* x     = (const float*)d_in[0];
  const float* w_qkv = (const float*)d_in[1];
  const float* b_qkv = (const float*)d_in[2];
  const float* w_out = (const float*)d_in[3];
  const float* b_out = (const float*)d_in[4];
  float* out = (float*)d_out;

  char* ws = (char*)d_ws;
  f16* xh    = (f16*)(ws);                        // 16,777,216  [8192][1024]
  f16* ctx   = (f16*)(ws);                        // aliased (xh dead after qkv_gemm)
  f16* wqkvT = (f16*)(ws + 16777216);             //  6,291,456  [3072][1024]
  f16* woutT = (f16*)(ws + 23068672);             //  2,097,152  [1024][1024]
  f16* Qs    = (f16*)(ws + 25165824);             // 16,777,216  [64][2048][64] scaled
  f16* Kk    = (f16*)(ws + 41943040);             // 16,777,216  [64][2048][64]
  f16* Vt    = (f16*)(ws + 58720256);             // 16,777,216  [64][64][2048]

  cvt_x<<<4096, 256, 0, stream>>>(x, xh);
  tconv<<<dim3(96, 32), dim3(32, 8), 0, stream>>>(w_qkv, wqkvT, 1024, 3072);
  tconv<<<dim3(32, 32), dim3(32, 8), 0, stream>>>(w_out, woutT, 1024, 1024);
  qkv_gemm<<<dim3(32, 12), 512, 0, stream>>>(xh, wqkvT, b_qkv, Qs, Kk, Vt);
  attn<<<dim3(8, 64), 512, 0, stream>>>(Qs, Kk, Vt, ctx);
  proj_gemm<<<dim3(64, 8), 256, 0, stream>>>(ctx, woutT, b_out, out);
}

// Round 6
// 257.780 us; speedup vs baseline: 1.0827x; 1.0195x over previous
//
#include <hip/hip_runtime.h>

// MultiheadAttention: B=4,S=2048,C=1024,E=1024,H=16,D=64. fp32 in/out.
// Pipeline: cvt x->f16; transpose+cvt w_qkv,w_out; QKV GEMM (f16 MFMA, fp32 acc)
// -> Q(scaled)/K [B,H,S,D], V^T [B,H,D,S]; flash attention -> ctx [tok][E];
// out-proj GEMM -> fp32 d_out. Needs 72MB workspace.
//
// R7: attn: full-rate 16x16x32 PV via key-permutation trick; 512-thr blocks.
// R8: attn: permuted-key lV (PV B-frag = one b128); XCD swizzle (bh per XCD).
// R9: GEMMs: XCD swizzle (A-slice per XCD, FETCH 135->49MB); BK=64 +
// XOR-swizzled LDS (conflicts 0). 74.7us but stage latency serial (2-barrier).
// R10/R11: 256^2 8-wave phased schedule REGRESSED (86-100us): 384 blocks at
// 1 block/CU = 1.5 dispatch rounds -> 33% tail idle; abandoned.
// R12: back to 128^2 skeleton + LDS DOUBLE-BUFFER with EARLY-ISSUE staging:
// loop t { issue stage(t+1)->buf^1 (8 gload_lds); ds_read+MFMA from buf;
// vmcnt(0); barrier; }  -- stage latency now overlaps compute(t) instead of
// sitting serial between two barriers. Race-free: buf^1's readers finished at
// the t-1 barrier; stage(t+1) completion enforced before t+1's reads.

typedef _Float16 f16;
typedef f16 f16x2 __attribute__((ext_vector_type(2)));
typedef f16 f16x4 __attribute__((ext_vector_type(4)));
typedef f16 f16x8 __attribute__((ext_vector_type(8)));
typedef float f32x4 __attribute__((ext_vector_type(4)));

typedef const __attribute__((address_space(1))) void* gas_ptr;
typedef __attribute__((address_space(3))) void* lds_ptr;

__device__ __forceinline__ void load_lds16(const void* g, void* s) {
  __builtin_amdgcn_global_load_lds((gas_ptr)g, (lds_ptr)s, 16, 0, 0);
}

__device__ __forceinline__ f32x4 mfma16(f16x8 a, f16x8 b, f32x4 c) {
  return __builtin_amdgcn_mfma_f32_16x16x32_f16(a, b, c, 0, 0, 0);
}

__device__ __forceinline__ f16x2 pk2(float a, float b) {
  return __builtin_bit_cast(f16x2, __builtin_amdgcn_cvt_pkrtz(a, b));
}

// ---------------- x: fp32 -> fp16 (8 elems/thread) ----------------
__global__ __launch_bounds__(256) void cvt_x(const float* __restrict__ in, f16* __restrict__ out) {
  int i = blockIdx.x * 256 + threadIdx.x;
  const float4* p = (const float4*)in;
  float4 a = p[2 * i], b = p[2 * i + 1];
  f16x8 o;
  o[0] = (f16)a.x; o[1] = (f16)a.y; o[2] = (f16)a.z; o[3] = (f16)a.w;
  o[4] = (f16)b.x; o[5] = (f16)b.y; o[6] = (f16)b.z; o[7] = (f16)b.w;
  *(f16x8*)(out + 8 * (long)i) = o;
}

// ------------- transpose + convert: in[R][C] f32 -> out[C][R] f16 -------------
__global__ __launch_bounds__(256) void tconv(const float* __restrict__ in, f16* __restrict__ out,
                                             int R, int C) {
  __shared__ float t[32][33];
  int c0 = blockIdx.x * 32, r0 = blockIdx.y * 32;
  int tx = threadIdx.x, ty = threadIdx.y;
#pragma unroll
  for (int j = 0; j < 4; ++j)
    t[ty + 8 * j][tx] = in[(long)(r0 + ty + 8 * j) * C + c0 + tx];
  __syncthreads();
#pragma unroll
  for (int j = 0; j < 4; ++j)
    out[(long)(c0 + ty + 8 * j) * R + r0 + tx] = (f16)t[tx][ty + 8 * j];
}

// ---------------- QKV GEMM (R12): [8192x1024] @ [1024x3072] + b ----------------
// 128x128 tile, 256 threads, BK=64, LDS dbuf + early-issue staging. grid (64,24).
__global__ __launch_bounds__(256) void qkv_gemm(const f16* __restrict__ A, const f16* __restrict__ BT,
                                                const float* __restrict__ bias,
                                                f16* __restrict__ Qs, f16* __restrict__ Kk,
                                                f16* __restrict__ Vt) {
  __shared__ __align__(16) f16 lA[2][128 * 64];
  __shared__ __align__(16) f16 lB[2][128 * 64];
  const int K = 1024;
  int tid = threadIdx.x, w = tid >> 6, lane = tid & 63, l16 = lane & 15, quad = lane >> 4;
  int wm = (w >> 1) * 64, wn = (w & 1) * 64;
  // XCD swizzle: XCD x owns blockM rows [8x,8x+8) (A slice 2MB, L2-resident).
  int id = blockIdx.y * gridDim.x + blockIdx.x;        // 1536 blocks
  int xcd = id & 7, cch = id >> 3;                     // cch in [0,192)
  int bx = xcd * 8 + (cch & 7), by = cch >> 3;         // by in [0,24)
  int blockM = bx * 128, blockN = by * 128;
  int sw = l16 & 7;
  f32x4 acc[4][4] = {};

  // stage K-tile kt into buffer kt&1. Physical 16B-chunk pc of row r holds
  // global chunk pc^(r&7) (T2, rule 21): dest linear, source pre-swizzled.
  auto stage = [&](int kt) {
    int k0 = kt * 64;
    f16* dA = lA[kt & 1];
    f16* dB = lB[kt & 1];
#pragma unroll
    for (int i = 0; i < 4; ++i) {
      int c = i * 256 + tid;                 // chunk id: row = c>>3, col-chunk = c&7
      int row = c >> 3;
      int sc = (c & 7) ^ (row & 7);
      load_lds16(A + (long)(blockM + row) * K + k0 + sc * 8, dA + c * 8);
      load_lds16(BT + (long)(blockN + row) * K + k0 + sc * 8, dB + c * 8);
    }
  };

  stage(0);
  asm volatile("s_waitcnt vmcnt(0)" ::: "memory");
  __builtin_amdgcn_s_barrier();

  for (int t = 0; t < 16; ++t) {
    // issue next tile's staging first: HBM/L2 latency overlaps compute below.
    // Target buffer's readers all finished at the t-1 barrier.
    if (t < 15) stage(t + 1);
    const f16* cA = lA[t & 1];
    const f16* cB = lB[t & 1];
#pragma unroll
    for (int ks = 0; ks < 2; ++ks) {
      f16x8 af[4], bf[4];
#pragma unroll
      for (int mb = 0; mb < 4; ++mb)
        af[mb] = *(const f16x8*)&cA[(wm + mb * 16 + l16) * 64 + ((ks * 4 + quad) ^ sw) * 8];
#pragma unroll
      for (int nb = 0; nb < 4; ++nb)
        bf[nb] = *(const f16x8*)&cB[(wn + nb * 16 + l16) * 64 + ((ks * 4 + quad) ^ sw) * 8];
      __builtin_amdgcn_s_setprio(1);
#pragma unroll
      for (int mb = 0; mb < 4; ++mb)
#pragma unroll
        for (int nb = 0; nb < 4; ++nb)
          acc[mb][nb] = mfma16(af[mb], bf[nb], acc[mb][nb]);
      __builtin_amdgcn_s_setprio(0);
    }
    // stage(t+1) must have landed before any wave reads buf[t+1].
    asm volatile("s_waitcnt vmcnt(0)" ::: "memory");
    __builtin_amdgcn_s_barrier();
  }

  int which = by >> 3;                           // 0=Q,1=K,2=V (block-uniform)
  const float SCALE = 0.18033688011112042f;      // log2(e)/sqrt(D)
#pragma unroll
  for (int nb = 0; nb < 4; ++nb) {
    int col = blockN + wn + nb * 16 + l16;
    int hd = col & 1023, h = hd >> 6, d = hd & 63;
    float bv = bias[col];
#pragma unroll
    for (int mb = 0; mb < 4; ++mb) {
      int row0 = blockM + wm + mb * 16 + quad * 4;   // 4 consecutive tokens
      int b = row0 >> 11, s0 = row0 & 2047;
      if (which == 2) {
        f16x2 a = pk2(acc[mb][nb][0] + bv, acc[mb][nb][1] + bv);
        f16x2 c = pk2(acc[mb][nb][2] + bv, acc[mb][nb][3] + bv);
        *(f16x4*)&Vt[((b * 16 + h) * 64 + d) * 2048 + s0] =
            __builtin_shufflevector(a, c, 0, 1, 2, 3);
      } else if (which == 0) {
#pragma unroll
        for (int r = 0; r < 4; ++r)
          Qs[((b * 16 + h) * 2048 + s0 + r) * 64 + d] = (f16)((acc[mb][nb][r] + bv) * SCALE);
      } else {
#pragma unroll
        for (int r = 0; r < 4; ++r)
          Kk[((b * 16 + h) * 2048 + s0 + r) * 64 + d] = (f16)(acc[mb][nb][r] + bv);
      }
    }
  }
}

// ---------------- Flash attention (R8) ----------------
// grid (8,64) -> XCD-swizzled to (qt, bh) so each XCD owns 8 bh (K/V L2-hot).
// 512 threads = 8 waves; wave owns 32 Q rows. Key tile 64 = 2 kp-groups of 32.
// Q pre-scaled -> exp2 domain; no online max (scores bounded).
// S^T = K*Q^T (16x16x32); P stays in registers (C-layout -> A-frag by reg
// concat under a key permutation applied identically to V).
// lV stores key 16h+4q+j of each kp-group at column 8q+4h+j, so the PV B-frag
// is ONE ds_read_b128 (stride-144 balanced banks). Row-sum via ones-B MFMA.
// lK/lV dbuf, reg prefetch, 1 barrier/kt, setprio around MFMA cluster.
__global__ __launch_bounds__(512, 4) void attn(const f16* __restrict__ Qs, const f16* __restrict__ Kk,
                                               const f16* __restrict__ Vt, f16* __restrict__ ctx) {
  __shared__ __align__(16) f16 lK[2][64 * 72];   // [key][d], stride 72
  __shared__ __align__(16) f16 lV[2][64 * 72];   // [d][permuted key]
  int id = blockIdx.y * gridDim.x + blockIdx.x;        // 512 blocks
  int swz = (id & 7) * 64 + (id >> 3);
  int qt = swz & 7, bh = swz >> 3;
  int tid = threadIdx.x, lane = tid & 63, l16 = lane & 15, quad = lane >> 4;
  int w = tid >> 6;                               // 8 waves
  const f16* Qbase = Qs + ((long)bh * 2048 + qt * 256 + w * 32) * 64;
  const f16* Kbh = Kk + (long)bh * 2048 * 64;
  const f16* Vbh = Vt + (long)bh * 64 * 2048;

  f16x8 qf[2][2];                                // B-frag: [n=row=rb*16+l16][k=d]
#pragma unroll
  for (int rb = 0; rb < 2; ++rb)
#pragma unroll
    for (int ks = 0; ks < 2; ++ks)
      qf[rb][ks] = *(const f16x8*)(Qbase + (rb * 16 + l16) * 64 + ks * 32 + quad * 8);

  f32x4 of[2][4] = {};
  f32x4 osum[2] = {};
  const f16 one = (f16)1.f;
  const f16x8 vone8 = {one, one, one, one, one, one, one, one};

  int rs = tid >> 3, o = (tid & 7) * 8;
  int koff = o & 31;
  int cperm = (o & 32) + ((koff & 12) << 1) + ((koff >> 4) << 2);  // kp*32+8qa+4h

  {
    *(float4*)&lK[0][rs * 72 + o] = *(const float4*)(Kbh + rs * 64 + o);
    float4 pv = *(const float4*)(Vbh + (long)rs * 2048 + o);
    f16x8 v8 = __builtin_bit_cast(f16x8, pv);
    *(f16x4*)&lV[0][rs * 72 + cperm] = __builtin_shufflevector(v8, v8, 0, 1, 2, 3);
    *(f16x4*)&lV[0][rs * 72 + cperm + 8] = __builtin_shufflevector(v8, v8, 4, 5, 6, 7);
  }
  __syncthreads();

  for (int kt = 0; kt < 32; ++kt) {
    int cur = kt & 1, nxt = cur ^ 1;

    float4 pk0, pv0;
    if (kt < 31) {
      int kb0 = (kt + 1) * 64;
      pk0 = *(const float4*)(Kbh + (kb0 + rs) * 64 + o);
      pv0 = *(const float4*)(Vbh + (long)rs * 2048 + kb0 + o);
    }

    __builtin_amdgcn_s_setprio(1);
#pragma unroll
    for (int kp = 0; kp < 2; ++kp) {             // 32-key pair
      f16x4 pah[2][2];                           // [rb][kbh]: packed exp, keys 4q..4q+3
#pragma unroll
      for (int kbh = 0; kbh < 2; ++kbh) {
        int kb = kp * 2 + kbh;
        f16x8 kf0 = *(const f16x8*)&lK[cur][(kb * 16 + l16) * 72 + quad * 8];
        f16x8 kf1 = *(const f16x8*)&lK[cur][(kb * 16 + l16) * 72 + 32 + quad * 8];
#pragma unroll
        for (int rb = 0; rb < 2; ++rb) {
          f32x4 z = {};
          z = mfma16(kf0, qf[rb][0], z);
          z = mfma16(kf1, qf[rb][1], z);
          float p0 = __builtin_amdgcn_exp2f(z[0]);
          float p1 = __builtin_amdgcn_exp2f(z[1]);
          float p2 = __builtin_amdgcn_exp2f(z[2]);
          float p3 = __builtin_amdgcn_exp2f(z[3]);
          pah[rb][kbh] = __builtin_shufflevector(pk2(p0, p1), pk2(p2, p3), 0, 1, 2, 3);
        }
      }
      f16x8 pa[2];
      pa[0] = __builtin_shufflevector(pah[0][0], pah[0][1], 0, 1, 2, 3, 4, 5, 6, 7);
      pa[1] = __builtin_shufflevector(pah[1][0], pah[1][1], 0, 1, 2, 3, 4, 5, 6, 7);

#pragma unroll
      for (int db = 0; db < 4; ++db) {
        f16x8 vf = *(const f16x8*)&lV[cur][(db * 16 + l16) * 72 + kp * 32 + quad * 8];
#pragma unroll
        for (int rb = 0; rb < 2; ++rb)
          of[rb][db] = mfma16(pa[rb], vf, of[rb][db]);
      }
#pragma unroll
      for (int rb = 0; rb < 2; ++rb)
        osum[rb] = mfma16(pa[rb], vone8, osum[rb]);
    }
    __builtin_amdgcn_s_setprio(0);

    if (kt < 31) {
      *(float4*)&lK[nxt][rs * 72 + o] = pk0;
      f16x8 v8 = __builtin_bit_cast(f16x8, pv0);
      *(f16x4*)&lV[nxt][rs * 72 + cperm] = __builtin_shufflevector(v8, v8, 0, 1, 2, 3);
      *(f16x4*)&lV[nxt][rs * 72 + cperm + 8] = __builtin_shufflevector(v8, v8, 4, 5, 6, 7);
      __syncthreads();
    }
  }

  int b = bh >> 4, h = bh & 15;
  long token0 = (long)b * 2048 + qt * 256 + w * 32;
#pragma unroll
  for (int rb = 0; rb < 2; ++rb) {
    float inv[4];
#pragma unroll
    for (int r = 0; r < 4; ++r) inv[r] = 1.0f / osum[rb][r];   // in-lane: same C-layout
#pragma unroll
    for (int db = 0; db < 4; ++db)
#pragma unroll
      for (int r = 0; r < 4; ++r)
        ctx[(token0 + rb * 16 + quad * 4 + r) * 1024 + h * 64 + db * 16 + l16] =
            (f16)(of[rb][db][r] * inv[r]);
  }
}

// ---------------- out-proj GEMM (R12): [8192x1024] @ [1024x1024] + b -> fp32 ----------------
// 128x128 tile, 256 threads, BK=64, LDS dbuf + early-issue staging. grid (64,8).
__global__ __launch_bounds__(256) void proj_gemm(const f16* __restrict__ A, const f16* __restrict__ BT,
                                                 const float* __restrict__ bias,
                                                 float* __restrict__ out) {
  __shared__ __align__(16) f16 lA[2][128 * 64];
  __shared__ __align__(16) f16 lB[2][128 * 64];
  const int K = 1024;
  int tid = threadIdx.x, w = tid >> 6, lane = tid & 63, l16 = lane & 15, quad = lane >> 4;
  int wm = (w >> 1) * 64, wn = (w & 1) * 64;
  // XCD swizzle: XCD x owns blockM rows [8x,8x+8); A and B slices both L2-fit.
  int id = blockIdx.y * gridDim.x + blockIdx.x;        // 512 blocks
  int xcd = id & 7, cch = id >> 3;                     // cch in [0,64)
  int bx = xcd * 8 + (cch & 7), by = cch >> 3;         // by in [0,8)
  int blockM = bx * 128, blockN = by * 128;
  int sw = l16 & 7;
  f32x4 acc[4][4] = {};

  auto stage = [&](int kt) {
    int k0 = kt * 64;
    f16* dA = lA[kt & 1];
    f16* dB = lB[kt & 1];
#pragma unroll
    for (int i = 0; i < 4; ++i) {
      int c = i * 256 + tid;
      int row = c >> 3;
      int sc = (c & 7) ^ (row & 7);
      load_lds16(A + (long)(blockM + row) * K + k0 + sc * 8, dA + c * 8);
      load_lds16(BT + (long)(blockN + row) * K + k0 + sc * 8, dB + c * 8);
    }
  };

  stage(0);
  asm volatile("s_waitcnt vmcnt(0)" ::: "memory");
  __builtin_amdgcn_s_barrier();

  for (int t = 0; t < 16; ++t) {
    if (t < 15) stage(t + 1);
    const f16* cA = lA[t & 1];
    const f16* cB = lB[t & 1];
#pragma unroll
    for (int ks = 0; ks < 2; ++ks) {
      f16x8 af[4], bf[4];
#pragma unroll
      for (int mb = 0; mb < 4; ++mb)
        af[mb] = *(const f16x8*)&cA[(wm + mb * 16 + l16) * 64 + ((ks * 4 + quad) ^ sw) * 8];
#pragma unroll
      for (int nb = 0; nb < 4; ++nb)
        bf[nb] = *(const f16x8*)&cB[(wn + nb * 16 + l16) * 64 + ((ks * 4 + quad) ^ sw) * 8];
      __builtin_amdgcn_s_setprio(1);
#pragma unroll
      for (int mb = 0; mb < 4; ++mb)
#pragma unroll
        for (int nb = 0; nb < 4; ++nb)
          acc[mb][nb] = mfma16(af[mb], bf[nb], acc[mb][nb]);
      __builtin_amdgcn_s_setprio(0);
    }
    asm volatile("s_waitcnt vmcnt(0)" ::: "memory");
    __builtin_amdgcn_s_barrier();
  }

#pragma unroll
  for (int nb = 0; nb < 4; ++nb) {
    int col = blockN + wn + nb * 16 + l16;
    float bv = bias[col];
#pragma unroll
    for (int mb = 0; mb < 4; ++mb) {
#pragma unroll
      for (int r = 0; r < 4; ++r) {
        int row = blockM + wm + mb * 16 + quad * 4 + r;
        out[(long)row * 1024 + col] = acc[mb][nb][r] + bv;
      }
    }
  }
}

extern "C" void kernel_launch(void* const* d_in, const int* in_sizes, int n_in,
                              void* d_out, int out_size, void* d_ws, size_t ws_size,
                              hipStream_t stream) {
  const float* x     = (const float*)d_in[0];
  const float* w_qkv = (const float*)d_in[1];
  const float* b_qkv = (const float*)d_in[2];
  const float* w_out = (const float*)d_in[3];
  const float* b_out = (const float*)d_in[4];
  float* out = (float*)d_out;

  char* ws = (char*)d_ws;
  f16* xh    = (f16*)(ws);                        // 16,777,216  [8192][1024]
  f16* ctx   = (f16*)(ws);                        // aliased (xh dead after qkv_gemm)
  f16* wqkvT = (f16*)(ws + 16777216);             //  6,291,456  [3072][1024]
  f16* woutT = (f16*)(ws + 23068672);             //  2,097,152  [1024][1024]
  f16* Qs    = (f16*)(ws + 25165824);             // 16,777,216  [64][2048][64] scaled
  f16* Kk    = (f16*)(ws + 41943040);             // 16,777,216  [64][2048][64]
  f16* Vt    = (f16*)(ws + 58720256);             // 16,777,216  [64][64][2048]

  cvt_x<<<4096, 256, 0, stream>>>(x, xh);
  tconv<<<dim3(96, 32), dim3(32, 8), 0, stream>>>(w_qkv, wqkvT, 1024, 3072);
  tconv<<<dim3(32, 32), dim3(32, 8), 0, stream>>>(w_out, woutT, 1024, 1024);
  qkv_gemm<<<dim3(64, 24), 256, 0, stream>>>(xh, wqkvT, b_qkv, Qs, Kk, Vt);
  attn<<<dim3(8, 64), 512, 0, stream>>>(Qs, Kk, Vt, ctx);
  proj_gemm<<<dim3(64, 8), 256, 0, stream>>>(ctx, woutT, b_out, out);
}

// Round 7
// 255.770 us; speedup vs baseline: 1.0912x; 1.0079x over previous
//
#include <hip/hip_runtime.h>

// MultiheadAttention: B=4,S=2048,C=1024,E=1024,H=16,D=64. fp32 in/out.
// Pipeline: prep (cvt x->f16 + transpose w_qkv,w_out); QKV GEMM (f16 MFMA,
// fp32 acc) -> Q(scaled)/K [B,H,S,D], V^T [B,H,D,S]; flash attention ->
// ctx [tok][E]; out-proj GEMM -> fp32 d_out. 72MB workspace.
//
// R7: attn: full-rate 16x16x32 PV via key-permutation trick.
// R8: attn: permuted-key lV; XCD swizzle (bh per XCD, K/V L2-hot).
// R9: GEMMs: XCD swizzle (A-slice per XCD); BK=64 + XOR-swizzled LDS.
// R12: GEMMs: LDS dbuf + early-issue staging (stage t+1 before compute t).
// R13: (a) attn: 256-thr blocks (4 waves, 128 q-rows), grid 16x64 -> 4
// blocks/CU = 4 independent barrier domains (was 2); (b) attn LDS stride
// 72->64 + XOR-chunk swizzle both sides; lK staged via global_load_lds
// (linear dest, pre-XOR source; no ds_write), lV reg-staged to XOR'd chunks
// -> all LDS ops bank-minimal (kills the 8.4M conflict cycles);
// (c) cvt_x + 2x tconv fused into one prep kernel (6 -> 4 dispatches).

typedef _Float16 f16;
typedef f16 f16x2 __attribute__((ext_vector_type(2)));
typedef f16 f16x4 __attribute__((ext_vector_type(4)));
typedef f16 f16x8 __attribute__((ext_vector_type(8)));
typedef float f32x4 __attribute__((ext_vector_type(4)));

typedef const __attribute__((address_space(1))) void* gas_ptr;
typedef __attribute__((address_space(3))) void* lds_ptr;

__device__ __forceinline__ void load_lds16(const void* g, void* s) {
  __builtin_amdgcn_global_load_lds((gas_ptr)g, (lds_ptr)s, 16, 0, 0);
}

__device__ __forceinline__ f32x4 mfma16(f16x8 a, f16x8 b, f32x4 c) {
  return __builtin_amdgcn_mfma_f32_16x16x32_f16(a, b, c, 0, 0, 0);
}

__device__ __forceinline__ f16x2 pk2(float a, float b) {
  return __builtin_bit_cast(f16x2, __builtin_amdgcn_cvt_pkrtz(a, b));
}

// ---------------- prep: cvt_x + tconv(w_qkv) + tconv(w_out), fused ----------------
// grid 8192 x 256thr: [0,4096) cvt; [4096,7168) wqkv T; [7168,8192) wout T.
__global__ __launch_bounds__(256) void prep(const float* __restrict__ x, f16* __restrict__ xh,
                                            const float* __restrict__ w_qkv, f16* __restrict__ wqkvT,
                                            const float* __restrict__ w_out, f16* __restrict__ woutT) {
  __shared__ float t[32][33];
  int bid = blockIdx.x, tid = threadIdx.x;
  if (bid < 4096) {
    long i = (long)bid * 256 + tid;
    const float4* p = (const float4*)x;
    float4 a = p[2 * i], b = p[2 * i + 1];
    f16x8 o;
    o[0] = (f16)a.x; o[1] = (f16)a.y; o[2] = (f16)a.z; o[3] = (f16)a.w;
    o[4] = (f16)b.x; o[5] = (f16)b.y; o[6] = (f16)b.z; o[7] = (f16)b.w;
    *(f16x8*)(xh + 8 * i) = o;
    return;
  }
  const float* in;
  f16* out;
  int R, C, c0, r0;
  if (bid < 7168) {
    int r = bid - 4096;                       // wqkv: in[1024][3072] -> out[3072][1024]
    in = w_qkv; out = wqkvT; R = 1024; C = 3072;
    c0 = (r % 96) * 32; r0 = (r / 96) * 32;
  } else {
    int r = bid - 7168;                       // wout: in[1024][1024] -> out[1024][1024]
    in = w_out; out = woutT; R = 1024; C = 1024;
    c0 = (r & 31) * 32; r0 = (r >> 5) * 32;
  }
  int tx = tid & 31, ty = tid >> 5;
#pragma unroll
  for (int j = 0; j < 4; ++j)
    t[ty + 8 * j][tx] = in[(long)(r0 + ty + 8 * j) * C + c0 + tx];
  __syncthreads();
#pragma unroll
  for (int j = 0; j < 4; ++j)
    out[(long)(c0 + ty + 8 * j) * R + r0 + tx] = (f16)t[tx][ty + 8 * j];
}

// ---------------- QKV GEMM (R12): [8192x1024] @ [1024x3072] + b ----------------
// 128x128 tile, 256 threads, BK=64, LDS dbuf + early-issue staging. grid (64,24).
__global__ __launch_bounds__(256) void qkv_gemm(const f16* __restrict__ A, const f16* __restrict__ BT,
                                                const float* __restrict__ bias,
                                                f16* __restrict__ Qs, f16* __restrict__ Kk,
                                                f16* __restrict__ Vt) {
  __shared__ __align__(16) f16 lA[2][128 * 64];
  __shared__ __align__(16) f16 lB[2][128 * 64];
  const int K = 1024;
  int tid = threadIdx.x, w = tid >> 6, lane = tid & 63, l16 = lane & 15, quad = lane >> 4;
  int wm = (w >> 1) * 64, wn = (w & 1) * 64;
  // XCD swizzle: XCD x owns blockM rows [8x,8x+8) (A slice 2MB, L2-resident).
  int id = blockIdx.y * gridDim.x + blockIdx.x;        // 1536 blocks
  int xcd = id & 7, cch = id >> 3;                     // cch in [0,192)
  int bx = xcd * 8 + (cch & 7), by = cch >> 3;         // by in [0,24)
  int blockM = bx * 128, blockN = by * 128;
  int sw = l16 & 7;
  f32x4 acc[4][4] = {};

  // stage K-tile kt into buffer kt&1. Physical 16B-chunk pc of row r holds
  // global chunk pc^(r&7) (T2, rule 21): dest linear, source pre-swizzled.
  auto stage = [&](int kt) {
    int k0 = kt * 64;
    f16* dA = lA[kt & 1];
    f16* dB = lB[kt & 1];
#pragma unroll
    for (int i = 0; i < 4; ++i) {
      int c = i * 256 + tid;                 // chunk id: row = c>>3, col-chunk = c&7
      int row = c >> 3;
      int sc = (c & 7) ^ (row & 7);
      load_lds16(A + (long)(blockM + row) * K + k0 + sc * 8, dA + c * 8);
      load_lds16(BT + (long)(blockN + row) * K + k0 + sc * 8, dB + c * 8);
    }
  };

  stage(0);
  asm volatile("s_waitcnt vmcnt(0)" ::: "memory");
  __builtin_amdgcn_s_barrier();

  for (int t = 0; t < 16; ++t) {
    // issue next tile's staging first: HBM/L2 latency overlaps compute below.
    if (t < 15) stage(t + 1);
    const f16* cA = lA[t & 1];
    const f16* cB = lB[t & 1];
#pragma unroll
    for (int ks = 0; ks < 2; ++ks) {
      f16x8 af[4], bf[4];
#pragma unroll
      for (int mb = 0; mb < 4; ++mb)
        af[mb] = *(const f16x8*)&cA[(wm + mb * 16 + l16) * 64 + ((ks * 4 + quad) ^ sw) * 8];
#pragma unroll
      for (int nb = 0; nb < 4; ++nb)
        bf[nb] = *(const f16x8*)&cB[(wn + nb * 16 + l16) * 64 + ((ks * 4 + quad) ^ sw) * 8];
      __builtin_amdgcn_s_setprio(1);
#pragma unroll
      for (int mb = 0; mb < 4; ++mb)
#pragma unroll
        for (int nb = 0; nb < 4; ++nb)
          acc[mb][nb] = mfma16(af[mb], bf[nb], acc[mb][nb]);
      __builtin_amdgcn_s_setprio(0);
    }
    asm volatile("s_waitcnt vmcnt(0)" ::: "memory");
    __builtin_amdgcn_s_barrier();
  }

  int which = by >> 3;                           // 0=Q,1=K,2=V (block-uniform)
  const float SCALE = 0.18033688011112042f;      // log2(e)/sqrt(D)
#pragma unroll
  for (int nb = 0; nb < 4; ++nb) {
    int col = blockN + wn + nb * 16 + l16;
    int hd = col & 1023, h = hd >> 6, d = hd & 63;
    float bv = bias[col];
#pragma unroll
    for (int mb = 0; mb < 4; ++mb) {
      int row0 = blockM + wm + mb * 16 + quad * 4;   // 4 consecutive tokens
      int b = row0 >> 11, s0 = row0 & 2047;
      if (which == 2) {
        f16x2 a = pk2(acc[mb][nb][0] + bv, acc[mb][nb][1] + bv);
        f16x2 c = pk2(acc[mb][nb][2] + bv, acc[mb][nb][3] + bv);
        *(f16x4*)&Vt[((b * 16 + h) * 64 + d) * 2048 + s0] =
            __builtin_shufflevector(a, c, 0, 1, 2, 3);
      } else if (which == 0) {
#pragma unroll
        for (int r = 0; r < 4; ++r)
          Qs[((b * 16 + h) * 2048 + s0 + r) * 64 + d] = (f16)((acc[mb][nb][r] + bv) * SCALE);
      } else {
#pragma unroll
        for (int r = 0; r < 4; ++r)
          Kk[((b * 16 + h) * 2048 + s0 + r) * 64 + d] = (f16)(acc[mb][nb][r] + bv);
      }
    }
  }
}

// ---------------- Flash attention (R13) ----------------
// grid (16,64) XCD-swizzled: each XCD owns 8 bh x 16 q-tiles (K/V L2-hot).
// 256 threads = 4 waves; wave owns 32 Q rows -> 4 blocks/CU, 4 barrier domains.
// Key tile 64 = 2 kp-groups of 32. Q pre-scaled -> exp2 domain; no online max.
// S^T = K*Q^T; P in registers; PV full-rate via key permutation (R7/R8).
// LDS [64][64] per tile, 16B-chunk XOR swizzle c^=(row&7) on BOTH sides:
// lK staged by global_load_lds (linear dest, pre-XOR source); lV reg-staged
// (permuted cols, XOR'd physical chunks). All LDS ops bank-minimal.
__global__ __launch_bounds__(256, 4) void attn(const f16* __restrict__ Qs, const f16* __restrict__ Kk,
                                               const f16* __restrict__ Vt, f16* __restrict__ ctx) {
  __shared__ __align__(16) f16 lK[2][64 * 64];   // [key][d], chunk-XOR
  __shared__ __align__(16) f16 lV[2][64 * 64];   // [d][perm key], chunk-XOR
  int id = blockIdx.y * gridDim.x + blockIdx.x;        // 1024 blocks
  int xcd = id & 7, rr = id >> 3;                      // rr in [0,128)
  int qt = rr & 15, bh = xcd * 8 + (rr >> 4);
  int tid = threadIdx.x, lane = tid & 63, l16 = lane & 15, quad = lane >> 4;
  int w = tid >> 6;                               // 4 waves
  int swr = l16 & 7;
  const f16* Qbase = Qs + ((long)bh * 2048 + qt * 128 + w * 32) * 64;
  const f16* Kbh = Kk + (long)bh * 2048 * 64;
  const f16* Vbh = Vt + (long)bh * 64 * 2048;

  f16x8 qf[2][2];                                // B-frag: [n=row=rb*16+l16][k=d]
#pragma unroll
  for (int rb = 0; rb < 2; ++rb)
#pragma unroll
    for (int ks = 0; ks < 2; ++ks)
      qf[rb][ks] = *(const f16x8*)(Qbase + (rb * 16 + l16) * 64 + ks * 32 + quad * 8);

  f32x4 of[2][4] = {};
  f32x4 osum[2] = {};
  const f16 one = (f16)1.f;
  const f16x8 vone8 = {one, one, one, one, one, one, one, one};

  // staging: thread covers rows rs and rs+32, col-group o (8 f16 = 16B).
  int rs = tid >> 3, o = (tid & 7) * 8, c1 = tid & 7;
  int jj = rs & 7;                                // == (rs+32)&7
  // lV logical perm (R8): keys 16h+4qa+j of a kp-group -> col 8qa+4h+j.
  int koff = o & 31;
  int Lp = (o & 32) + ((koff & 12) << 1) + ((koff >> 4) << 2);
  // physical byte offset of logical 4-elem group L in row r:
  //   (((L>>3) ^ (r&7)) << 4) + ((L & 4) << 1)
  int pv0b = (((Lp >> 3) ^ jj) << 4) + ((Lp & 4) << 1);
  int pv1b = ((((Lp >> 3) + 1) ^ jj) << 4) + ((Lp & 4) << 1);

  auto stageK = [&](int kt) {                     // 2x global_load_lds, linear dest
    int kb0 = kt * 64;
    f16* dst = lK[kt & 1];
    int r0 = rs, r1 = rs + 32;
    load_lds16(Kbh + (kb0 + r0) * 64 + (c1 ^ (r0 & 7)) * 8, dst + tid * 8);
    load_lds16(Kbh + (kb0 + r1) * 64 + (c1 ^ (r1 & 7)) * 8, dst + (256 + tid) * 8);
  };
  auto writeV = [&](int buf, float4 va, float4 vb) {
    f16* d0 = lV[buf] + rs * 64;
    f16* d1 = lV[buf] + (rs + 32) * 64;
    f16x8 a8 = __builtin_bit_cast(f16x8, va);
    f16x8 b8 = __builtin_bit_cast(f16x8, vb);
    *(f16x4*)((char*)d0 + pv0b) = __builtin_shufflevector(a8, a8, 0, 1, 2, 3);
    *(f16x4*)((char*)d0 + pv1b) = __builtin_shufflevector(a8, a8, 4, 5, 6, 7);
    *(f16x4*)((char*)d1 + pv0b) = __builtin_shufflevector(b8, b8, 0, 1, 2, 3);
    *(f16x4*)((char*)d1 + pv1b) = __builtin_shufflevector(b8, b8, 4, 5, 6, 7);
  };

  // preload tile 0
  {
    stageK(0);
    float4 va = *(const float4*)(Vbh + (long)rs * 2048 + o);
    float4 vb = *(const float4*)(Vbh + (long)(rs + 32) * 2048 + o);
    writeV(0, va, vb);
    asm volatile("s_waitcnt vmcnt(0)" ::: "memory");
    __builtin_amdgcn_s_barrier();
  }

  for (int kt = 0; kt < 32; ++kt) {
    int cur = kt & 1, nxt = cur ^ 1;

    // issue next tile's loads first: latency overlaps compute below
    float4 va, vb;
    if (kt < 31) {
      int kb0 = (kt + 1) * 64;
      stageK(kt + 1);
      va = *(const float4*)(Vbh + (long)rs * 2048 + kb0 + o);
      vb = *(const float4*)(Vbh + (long)(rs + 32) * 2048 + kb0 + o);
    }

    __builtin_amdgcn_s_setprio(1);
#pragma unroll
    for (int kp = 0; kp < 2; ++kp) {             // 32-key pair
      f16x4 pah[2][2];                           // [rb][kbh]: packed exp, keys 4q..4q+3
#pragma unroll
      for (int kbh = 0; kbh < 2; ++kbh) {
        int kb = kp * 2 + kbh;
        f16x8 kf0 = *(const f16x8*)&lK[cur][(kb * 16 + l16) * 64 + ((quad ^ swr) << 3)];
        f16x8 kf1 = *(const f16x8*)&lK[cur][(kb * 16 + l16) * 64 + (((4 + quad) ^ swr) << 3)];
#pragma unroll
        for (int rb = 0; rb < 2; ++rb) {
          f32x4 z = {};
          z = mfma16(kf0, qf[rb][0], z);
          z = mfma16(kf1, qf[rb][1], z);
          float p0 = __builtin_amdgcn_exp2f(z[0]);
          float p1 = __builtin_amdgcn_exp2f(z[1]);
          float p2 = __builtin_amdgcn_exp2f(z[2]);
          float p3 = __builtin_amdgcn_exp2f(z[3]);
          pah[rb][kbh] = __builtin_shufflevector(pk2(p0, p1), pk2(p2, p3), 0, 1, 2, 3);
        }
      }
      // A-frag (16x16x32): slot (quad,j) holds permuted key set; k-sum invariant
      f16x8 pa[2];
      pa[0] = __builtin_shufflevector(pah[0][0], pah[0][1], 0, 1, 2, 3, 4, 5, 6, 7);
      pa[1] = __builtin_shufflevector(pah[1][0], pah[1][1], 0, 1, 2, 3, 4, 5, 6, 7);

      // O += P V (full-rate); V key-permuted -> one b128 per db
#pragma unroll
      for (int db = 0; db < 4; ++db) {
        f16x8 vf = *(const f16x8*)&lV[cur][(db * 16 + l16) * 64 + (((kp * 4 + quad) ^ swr) << 3)];
#pragma unroll
        for (int rb = 0; rb < 2; ++rb)
          of[rb][db] = mfma16(pa[rb], vf, of[rb][db]);
      }
#pragma unroll
      for (int rb = 0; rb < 2; ++rb)
        osum[rb] = mfma16(pa[rb], vone8, osum[rb]);
    }
    __builtin_amdgcn_s_setprio(0);

    if (kt < 31) {
      writeV(nxt, va, vb);
      asm volatile("s_waitcnt vmcnt(0)" ::: "memory");   // lK[nxt] landed
      __builtin_amdgcn_s_barrier();
    }
  }

  int b = bh >> 4, h = bh & 15;
  long token0 = (long)b * 2048 + qt * 128 + w * 32;
#pragma unroll
  for (int rb = 0; rb < 2; ++rb) {
    float inv[4];
#pragma unroll
    for (int r = 0; r < 4; ++r) inv[r] = 1.0f / osum[rb][r];   // in-lane: same C-layout
#pragma unroll
    for (int db = 0; db < 4; ++db)
#pragma unroll
      for (int r = 0; r < 4; ++r)
        ctx[(token0 + rb * 16 + quad * 4 + r) * 1024 + h * 64 + db * 16 + l16] =
            (f16)(of[rb][db][r] * inv[r]);
  }
}

// ---------------- out-proj GEMM (R12): [8192x1024] @ [1024x1024] + b -> fp32 ----------------
__global__ __launch_bounds__(256) void proj_gemm(const f16* __restrict__ A, const f16* __restrict__ BT,
                                                 const float* __restrict__ bias,
                                                 float* __restrict__ out) {
  __shared__ __align__(16) f16 lA[2][128 * 64];
  __shared__ __align__(16) f16 lB[2][128 * 64];
  const int K = 1024;
  int tid = threadIdx.x, w = tid >> 6, lane = tid & 63, l16 = lane & 15, quad = lane >> 4;
  int wm = (w >> 1) * 64, wn = (w & 1) * 64;
  int id = blockIdx.y * gridDim.x + blockIdx.x;        // 512 blocks
  int xcd = id & 7, cch = id >> 3;                     // cch in [0,64)
  int bx = xcd * 8 + (cch & 7), by = cch >> 3;         // by in [0,8)
  int blockM = bx * 128, blockN = by * 128;
  int sw = l16 & 7;
  f32x4 acc[4][4] = {};

  auto stage = [&](int kt) {
    int k0 = kt * 64;
    f16* dA = lA[kt & 1];
    f16* dB = lB[kt & 1];
#pragma unroll
    for (int i = 0; i < 4; ++i) {
      int c = i * 256 + tid;
      int row = c >> 3;
      int sc = (c & 7) ^ (row & 7);
      load_lds16(A + (long)(blockM + row) * K + k0 + sc * 8, dA + c * 8);
      load_lds16(BT + (long)(blockN + row) * K + k0 + sc * 8, dB + c * 8);
    }
  };

  stage(0);
  asm volatile("s_waitcnt vmcnt(0)" ::: "memory");
  __builtin_amdgcn_s_barrier();

  for (int t = 0; t < 16; ++t) {
    if (t < 15) stage(t + 1);
    const f16* cA = lA[t & 1];
    const f16* cB = lB[t & 1];
#pragma unroll
    for (int ks = 0; ks < 2; ++ks) {
      f16x8 af[4], bf[4];
#pragma unroll
      for (int mb = 0; mb < 4; ++mb)
        af[mb] = *(const f16x8*)&cA[(wm + mb * 16 + l16) * 64 + ((ks * 4 + quad) ^ sw) * 8];
#pragma unroll
      for (int nb = 0; nb < 4; ++nb)
        bf[nb] = *(const f16x8*)&cB[(wn + nb * 16 + l16) * 64 + ((ks * 4 + quad) ^ sw) * 8];
      __builtin_amdgcn_s_setprio(1);
#pragma unroll
      for (int mb = 0; mb < 4; ++mb)
#pragma unroll
        for (int nb = 0; nb < 4; ++nb)
          acc[mb][nb] = mfma16(af[mb], bf[nb], acc[mb][nb]);
      __builtin_amdgcn_s_setprio(0);
    }
    asm volatile("s_waitcnt vmcnt(0)" ::: "memory");
    __builtin_amdgcn_s_barrier();
  }

#pragma unroll
  for (int nb = 0; nb < 4; ++nb) {
    int col = blockN + wn + nb * 16 + l16;
    float bv = bias[col];
#pragma unroll
    for (int mb = 0; mb < 4; ++mb) {
#pragma unroll
      for (int r = 0; r < 4; ++r) {
        int row = blockM + wm + mb * 16 + quad * 4 + r;
        out[(long)row * 1024 + col] = acc[mb][nb][r] + bv;
      }
    }
  }
}

extern "C" void kernel_launch(void* const* d_in, const int* in_sizes, int n_in,
                              void* d_out, int out_size, void* d_ws, size_t ws_size,
                              hipStream_t stream) {
  const float* x     = (const float*)d_in[0];
  const float* w_qkv = (const float*)d_in[1];
  const float* b_qkv = (const float*)d_in[2];
  const float* w_out = (const float*)d_in[3];
  const float* b_out = (const float*)d_in[4];
  float* out = (float*)d_out;

  char* ws = (char*)d_ws;
  f16* xh    = (f16*)(ws);                        // 16,777,216  [8192][1024]
  f16* ctx   = (f16*)(ws);                        // aliased (xh dead after qkv_gemm)
  f16* wqkvT = (f16*)(ws + 16777216);             //  6,291,456  [3072][1024]
  f16* woutT = (f16*)(ws + 23068672);             //  2,097,152  [1024][1024]
  f16* Qs    = (f16*)(ws + 25165824);             // 16,777,216  [64][2048][64] scaled
  f16* Kk    = (f16*)(ws + 41943040);             // 16,777,216  [64][2048][64]
  f16* Vt    = (f16*)(ws + 58720256);             // 16,777,216  [64][64][2048]

  prep<<<8192, 256, 0, stream>>>(x, xh, w_qkv, wqkvT, w_out, woutT);
  qkv_gemm<<<dim3(64, 24), 256, 0, stream>>>(xh, wqkvT, b_qkv, Qs, Kk, Vt);
  attn<<<dim3(16, 64), 256, 0, stream>>>(Qs, Kk, Vt, ctx);
  proj_gemm<<<dim3(64, 8), 256, 0, stream>>>(ctx, woutT, b_out, out);
}

// Round 8
// 254.007 us; speedup vs baseline: 1.0988x; 1.0069x over previous
//
#include <hip/hip_runtime.h>

// MultiheadAttention: B=4,S=2048,C=1024,E=1024,H=16,D=64. fp32 in/out.
// Pipeline: prep (cvt x->f16 + transpose w_qkv,w_out); QKV GEMM (f16 MFMA,
// fp32 acc) -> Q(scaled)/K [B,H,S,D], V^T [B,H,D,S]; flash attention ->
// ctx [tok][E]; out-proj GEMM -> fp32 d_out. 72MB workspace.
//
// R7: attn: full-rate 16x16x32 PV via key-permutation trick.
// R8: attn: permuted-key lV; XCD swizzle (bh per XCD, K/V L2-hot).
// R9: GEMMs: XCD swizzle (A-slice per XCD); BK=64 + XOR-swizzled LDS.
// R12: GEMMs: LDS dbuf + early-issue staging (stage t+1 before compute t).
// R13: attn 256-thr REGRESSED (+6us): #blocks doubled -> per-CU K/V staging
// doubled (staging scales with #blocks, not q-rows). LDS swizzle itself good
// (conflicts 8.4M -> 0).
// R14: merge: R8 block shape (512 thr, 8 waves, 256 q-rows, grid 8x64 = 1x
// staging) + R13 conflict-free LDS (stride-64 XOR-chunk swizzle; lK via
// global_load_lds linear-dest/pre-XOR-source -- no K ds_write; lV reg-staged
// to XOR'd chunks; reads XOR with l16&7). Early-issue staging kept.

typedef _Float16 f16;
typedef f16 f16x2 __attribute__((ext_vector_type(2)));
typedef f16 f16x4 __attribute__((ext_vector_type(4)));
typedef f16 f16x8 __attribute__((ext_vector_type(8)));
typedef float f32x4 __attribute__((ext_vector_type(4)));

typedef const __attribute__((address_space(1))) void* gas_ptr;
typedef __attribute__((address_space(3))) void* lds_ptr;

__device__ __forceinline__ void load_lds16(const void* g, void* s) {
  __builtin_amdgcn_global_load_lds((gas_ptr)g, (lds_ptr)s, 16, 0, 0);
}

__device__ __forceinline__ f32x4 mfma16(f16x8 a, f16x8 b, f32x4 c) {
  return __builtin_amdgcn_mfma_f32_16x16x32_f16(a, b, c, 0, 0, 0);
}

__device__ __forceinline__ f16x2 pk2(float a, float b) {
  return __builtin_bit_cast(f16x2, __builtin_amdgcn_cvt_pkrtz(a, b));
}

// ---------------- prep: cvt_x + tconv(w_qkv) + tconv(w_out), fused ----------------
// grid 8192 x 256thr: [0,4096) cvt; [4096,7168) wqkv T; [7168,8192) wout T.
__global__ __launch_bounds__(256) void prep(const float* __restrict__ x, f16* __restrict__ xh,
                                            const float* __restrict__ w_qkv, f16* __restrict__ wqkvT,
                                            const float* __restrict__ w_out, f16* __restrict__ woutT) {
  __shared__ float t[32][33];
  int bid = blockIdx.x, tid = threadIdx.x;
  if (bid < 4096) {
    long i = (long)bid * 256 + tid;
    const float4* p = (const float4*)x;
    float4 a = p[2 * i], b = p[2 * i + 1];
    f16x8 o;
    o[0] = (f16)a.x; o[1] = (f16)a.y; o[2] = (f16)a.z; o[3] = (f16)a.w;
    o[4] = (f16)b.x; o[5] = (f16)b.y; o[6] = (f16)b.z; o[7] = (f16)b.w;
    *(f16x8*)(xh + 8 * i) = o;
    return;
  }
  const float* in;
  f16* out;
  int R, C, c0, r0;
  if (bid < 7168) {
    int r = bid - 4096;                       // wqkv: in[1024][3072] -> out[3072][1024]
    in = w_qkv; out = wqkvT; R = 1024; C = 3072;
    c0 = (r % 96) * 32; r0 = (r / 96) * 32;
  } else {
    int r = bid - 7168;                       // wout: in[1024][1024] -> out[1024][1024]
    in = w_out; out = woutT; R = 1024; C = 1024;
    c0 = (r & 31) * 32; r0 = (r >> 5) * 32;
  }
  int tx = tid & 31, ty = tid >> 5;
#pragma unroll
  for (int j = 0; j < 4; ++j)
    t[ty + 8 * j][tx] = in[(long)(r0 + ty + 8 * j) * C + c0 + tx];
  __syncthreads();
#pragma unroll
  for (int j = 0; j < 4; ++j)
    out[(long)(c0 + ty + 8 * j) * R + r0 + tx] = (f16)t[tx][ty + 8 * j];
}

// ---------------- QKV GEMM (R12): [8192x1024] @ [1024x3072] + b ----------------
// 128x128 tile, 256 threads, BK=64, LDS dbuf + early-issue staging. grid (64,24).
__global__ __launch_bounds__(256) void qkv_gemm(const f16* __restrict__ A, const f16* __restrict__ BT,
                                                const float* __restrict__ bias,
                                                f16* __restrict__ Qs, f16* __restrict__ Kk,
                                                f16* __restrict__ Vt) {
  __shared__ __align__(16) f16 lA[2][128 * 64];
  __shared__ __align__(16) f16 lB[2][128 * 64];
  const int K = 1024;
  int tid = threadIdx.x, w = tid >> 6, lane = tid & 63, l16 = lane & 15, quad = lane >> 4;
  int wm = (w >> 1) * 64, wn = (w & 1) * 64;
  // XCD swizzle: XCD x owns blockM rows [8x,8x+8) (A slice 2MB, L2-resident).
  int id = blockIdx.y * gridDim.x + blockIdx.x;        // 1536 blocks
  int xcd = id & 7, cch = id >> 3;                     // cch in [0,192)
  int bx = xcd * 8 + (cch & 7), by = cch >> 3;         // by in [0,24)
  int blockM = bx * 128, blockN = by * 128;
  int sw = l16 & 7;
  f32x4 acc[4][4] = {};

  // stage K-tile kt into buffer kt&1. Physical 16B-chunk pc of row r holds
  // global chunk pc^(r&7) (T2, rule 21): dest linear, source pre-swizzled.
  auto stage = [&](int kt) {
    int k0 = kt * 64;
    f16* dA = lA[kt & 1];
    f16* dB = lB[kt & 1];
#pragma unroll
    for (int i = 0; i < 4; ++i) {
      int c = i * 256 + tid;                 // chunk id: row = c>>3, col-chunk = c&7
      int row = c >> 3;
      int sc = (c & 7) ^ (row & 7);
      load_lds16(A + (long)(blockM + row) * K + k0 + sc * 8, dA + c * 8);
      load_lds16(BT + (long)(blockN + row) * K + k0 + sc * 8, dB + c * 8);
    }
  };

  stage(0);
  asm volatile("s_waitcnt vmcnt(0)" ::: "memory");
  __builtin_amdgcn_s_barrier();

  for (int t = 0; t < 16; ++t) {
    // issue next tile's staging first: HBM/L2 latency overlaps compute below.
    if (t < 15) stage(t + 1);
    const f16* cA = lA[t & 1];
    const f16* cB = lB[t & 1];
#pragma unroll
    for (int ks = 0; ks < 2; ++ks) {
      f16x8 af[4], bf[4];
#pragma unroll
      for (int mb = 0; mb < 4; ++mb)
        af[mb] = *(const f16x8*)&cA[(wm + mb * 16 + l16) * 64 + ((ks * 4 + quad) ^ sw) * 8];
#pragma unroll
      for (int nb = 0; nb < 4; ++nb)
        bf[nb] = *(const f16x8*)&cB[(wn + nb * 16 + l16) * 64 + ((ks * 4 + quad) ^ sw) * 8];
      __builtin_amdgcn_s_setprio(1);
#pragma unroll
      for (int mb = 0; mb < 4; ++mb)
#pragma unroll
        for (int nb = 0; nb < 4; ++nb)
          acc[mb][nb] = mfma16(af[mb], bf[nb], acc[mb][nb]);
      __builtin_amdgcn_s_setprio(0);
    }
    asm volatile("s_waitcnt vmcnt(0)" ::: "memory");
    __builtin_amdgcn_s_barrier();
  }

  int which = by >> 3;                           // 0=Q,1=K,2=V (block-uniform)
  const float SCALE = 0.18033688011112042f;      // log2(e)/sqrt(D)
#pragma unroll
  for (int nb = 0; nb < 4; ++nb) {
    int col = blockN + wn + nb * 16 + l16;
    int hd = col & 1023, h = hd >> 6, d = hd & 63;
    float bv = bias[col];
#pragma unroll
    for (int mb = 0; mb < 4; ++mb) {
      int row0 = blockM + wm + mb * 16 + quad * 4;   // 4 consecutive tokens
      int b = row0 >> 11, s0 = row0 & 2047;
      if (which == 2) {
        f16x2 a = pk2(acc[mb][nb][0] + bv, acc[mb][nb][1] + bv);
        f16x2 c = pk2(acc[mb][nb][2] + bv, acc[mb][nb][3] + bv);
        *(f16x4*)&Vt[((b * 16 + h) * 64 + d) * 2048 + s0] =
            __builtin_shufflevector(a, c, 0, 1, 2, 3);
      } else if (which == 0) {
#pragma unroll
        for (int r = 0; r < 4; ++r)
          Qs[((b * 16 + h) * 2048 + s0 + r) * 64 + d] = (f16)((acc[mb][nb][r] + bv) * SCALE);
      } else {
#pragma unroll
        for (int r = 0; r < 4; ++r)
          Kk[((b * 16 + h) * 2048 + s0 + r) * 64 + d] = (f16)(acc[mb][nb][r] + bv);
      }
    }
  }
}

// ---------------- Flash attention (R14) ----------------
// grid (8,64) XCD-swizzled: XCD x owns bh in [8x,8x+8) (K/V L2-hot).
// 512 threads = 8 waves; wave owns 32 Q rows (block = 256 q-rows -> 1x staging).
// Key tile 64 = 2 kp-groups of 32. Q pre-scaled -> exp2 domain; no online max.
// S^T = K*Q^T; P in registers; PV full-rate via key permutation (R7/R8).
// LDS [64][64] per tile, 16B-chunk XOR swizzle c^=(row&7) on BOTH sides:
// lK staged by global_load_lds (linear dest, pre-XOR source; no ds_write);
// lV reg-staged (permuted cols, XOR'd physical chunks). Bank-minimal.
// lK/lV dbuf, early-issue staging, 1 barrier/kt, setprio around MFMA.
__global__ __launch_bounds__(512, 4) void attn(const f16* __restrict__ Qs, const f16* __restrict__ Kk,
                                               const f16* __restrict__ Vt, f16* __restrict__ ctx) {
  __shared__ __align__(16) f16 lK[2][64 * 64];   // [key][d], chunk-XOR
  __shared__ __align__(16) f16 lV[2][64 * 64];   // [d][perm key], chunk-XOR
  int id = blockIdx.y * gridDim.x + blockIdx.x;        // 512 blocks
  int swz = (id & 7) * 64 + (id >> 3);
  int qt = swz & 7, bh = swz >> 3;                     // XCD id&7 -> bh block
  int tid = threadIdx.x, lane = tid & 63, l16 = lane & 15, quad = lane >> 4;
  int w = tid >> 6;                               // 8 waves
  int swr = l16 & 7;
  const f16* Qbase = Qs + ((long)bh * 2048 + qt * 256 + w * 32) * 64;
  const f16* Kbh = Kk + (long)bh * 2048 * 64;
  const f16* Vbh = Vt + (long)bh * 64 * 2048;

  f16x8 qf[2][2];                                // B-frag: [n=row=rb*16+l16][k=d]
#pragma unroll
  for (int rb = 0; rb < 2; ++rb)
#pragma unroll
    for (int ks = 0; ks < 2; ++ks)
      qf[rb][ks] = *(const f16x8*)(Qbase + (rb * 16 + l16) * 64 + ks * 32 + quad * 8);

  f32x4 of[2][4] = {};
  f32x4 osum[2] = {};
  const f16 one = (f16)1.f;
  const f16x8 vone8 = {one, one, one, one, one, one, one, one};

  // staging: thread covers row rs, col-group o (8 f16 = 16B chunk c1).
  int rs = tid >> 3, o = (tid & 7) * 8, c1 = tid & 7;
  int jj = rs & 7;
  // lV logical perm (R8): keys 16h+4qa+j of a kp-group -> col 8qa+4h+j.
  int koff = o & 31;
  int Lp = (o & 32) + ((koff & 12) << 1) + ((koff >> 4) << 2);
  // physical byte offset of logical 4-elem group L in row r:
  //   (((L>>3) ^ (r&7)) << 4) + ((L & 4) << 1)
  int pv0b = (((Lp >> 3) ^ jj) << 4) + ((Lp & 4) << 1);
  int pv1b = ((((Lp >> 3) + 1) ^ jj) << 4) + ((Lp & 4) << 1);

  auto stageK = [&](int kt) {                     // 1x global_load_lds, linear dest
    int kb0 = kt * 64;
    f16* dst = lK[kt & 1];
    load_lds16(Kbh + (kb0 + rs) * 64 + (c1 ^ jj) * 8, dst + tid * 8);
  };
  auto writeV = [&](int buf, float4 va) {
    f16* d0 = lV[buf] + rs * 64;
    f16x8 a8 = __builtin_bit_cast(f16x8, va);
    *(f16x4*)((char*)d0 + pv0b) = __builtin_shufflevector(a8, a8, 0, 1, 2, 3);
    *(f16x4*)((char*)d0 + pv1b) = __builtin_shufflevector(a8, a8, 4, 5, 6, 7);
  };

  // preload tile 0
  {
    stageK(0);
    float4 va = *(const float4*)(Vbh + (long)rs * 2048 + o);
    writeV(0, va);
    asm volatile("s_waitcnt vmcnt(0)" ::: "memory");
    __builtin_amdgcn_s_barrier();
  }

  for (int kt = 0; kt < 32; ++kt) {
    int cur = kt & 1, nxt = cur ^ 1;

    // issue next tile's loads first: latency overlaps compute below.
    // lK[nxt]/lV[nxt] readers finished at the kt-1 barrier.
    float4 va;
    if (kt < 31) {
      int kb0 = (kt + 1) * 64;
      stageK(kt + 1);
      va = *(const float4*)(Vbh + (long)rs * 2048 + kb0 + o);
    }

    __builtin_amdgcn_s_setprio(1);
#pragma unroll
    for (int kp = 0; kp < 2; ++kp) {             // 32-key pair
      f16x4 pah[2][2];                           // [rb][kbh]: packed exp, keys 4q..4q+3
#pragma unroll
      for (int kbh = 0; kbh < 2; ++kbh) {
        int kb = kp * 2 + kbh;
        f16x8 kf0 = *(const f16x8*)&lK[cur][(kb * 16 + l16) * 64 + ((quad ^ swr) << 3)];
        f16x8 kf1 = *(const f16x8*)&lK[cur][(kb * 16 + l16) * 64 + (((4 + quad) ^ swr) << 3)];
#pragma unroll
        for (int rb = 0; rb < 2; ++rb) {
          f32x4 z = {};
          z = mfma16(kf0, qf[rb][0], z);
          z = mfma16(kf1, qf[rb][1], z);
          float p0 = __builtin_amdgcn_exp2f(z[0]);
          float p1 = __builtin_amdgcn_exp2f(z[1]);
          float p2 = __builtin_amdgcn_exp2f(z[2]);
          float p3 = __builtin_amdgcn_exp2f(z[3]);
          pah[rb][kbh] = __builtin_shufflevector(pk2(p0, p1), pk2(p2, p3), 0, 1, 2, 3);
        }
      }
      // A-frag (16x16x32): slot (quad,j) holds permuted key set; k-sum invariant
      f16x8 pa[2];
      pa[0] = __builtin_shufflevector(pah[0][0], pah[0][1], 0, 1, 2, 3, 4, 5, 6, 7);
      pa[1] = __builtin_shufflevector(pah[1][0], pah[1][1], 0, 1, 2, 3, 4, 5, 6, 7);

      // O += P V (full-rate); V key-permuted -> one b128 per db
#pragma unroll
      for (int db = 0; db < 4; ++db) {
        f16x8 vf = *(const f16x8*)&lV[cur][(db * 16 + l16) * 64 + (((kp * 4 + quad) ^ swr) << 3)];
#pragma unroll
        for (int rb = 0; rb < 2; ++rb)
          of[rb][db] = mfma16(pa[rb], vf, of[rb][db]);
      }
#pragma unroll
      for (int rb = 0; rb < 2; ++rb)
        osum[rb] = mfma16(pa[rb], vone8, osum[rb]);
    }
    __builtin_amdgcn_s_setprio(0);

    if (kt < 31) {
      writeV(nxt, va);
      asm volatile("s_waitcnt vmcnt(0)" ::: "memory");   // lK[nxt] landed
      __builtin_amdgcn_s_barrier();
    }
  }

  int b = bh >> 4, h = bh & 15;
  long token0 = (long)b * 2048 + qt * 256 + w * 32;
#pragma unroll
  for (int rb = 0; rb < 2; ++rb) {
    float inv[4];
#pragma unroll
    for (int r = 0; r < 4; ++r) inv[r] = 1.0f / osum[rb][r];   // in-lane: same C-layout
#pragma unroll
    for (int db = 0; db < 4; ++db)
#pragma unroll
      for (int r = 0; r < 4; ++r)
        ctx[(token0 + rb * 16 + quad * 4 + r) * 1024 + h * 64 + db * 16 + l16] =
            (f16)(of[rb][db][r] * inv[r]);
  }
}

// ---------------- out-proj GEMM (R12): [8192x1024] @ [1024x1024] + b -> fp32 ----------------
__global__ __launch_bounds__(256) void proj_gemm(const f16* __restrict__ A, const f16* __restrict__ BT,
                                                 const float* __restrict__ bias,
                                                 float* __restrict__ out) {
  __shared__ __align__(16) f16 lA[2][128 * 64];
  __shared__ __align__(16) f16 lB[2][128 * 64];
  const int K = 1024;
  int tid = threadIdx.x, w = tid >> 6, lane = tid & 63, l16 = lane & 15, quad = lane >> 4;
  int wm = (w >> 1) * 64, wn = (w & 1) * 64;
  int id = blockIdx.y * gridDim.x + blockIdx.x;        // 512 blocks
  int xcd = id & 7, cch = id >> 3;                     // cch in [0,64)
  int bx = xcd * 8 + (cch & 7), by = cch >> 3;         // by in [0,8)
  int blockM = bx * 128, blockN = by * 128;
  int sw = l16 & 7;
  f32x4 acc[4][4] = {};

  auto stage = [&](int kt) {
    int k0 = kt * 64;
    f16* dA = lA[kt & 1];
    f16* dB = lB[kt & 1];
#pragma unroll
    for (int i = 0; i < 4; ++i) {
      int c = i * 256 + tid;
      int row = c >> 3;
      int sc = (c & 7) ^ (row & 7);
      load_lds16(A + (long)(blockM + row) * K + k0 + sc * 8, dA + c * 8);
      load_lds16(BT + (long)(blockN + row) * K + k0 + sc * 8, dB + c * 8);
    }
  };

  stage(0);
  asm volatile("s_waitcnt vmcnt(0)" ::: "memory");
  __builtin_amdgcn_s_barrier();

  for (int t = 0; t < 16; ++t) {
    if (t < 15) stage(t + 1);
    const f16* cA = lA[t & 1];
    const f16* cB = lB[t & 1];
#pragma unroll
    for (int ks = 0; ks < 2; ++ks) {
      f16x8 af[4], bf[4];
#pragma unroll
      for (int mb = 0; mb < 4; ++mb)
        af[mb] = *(const f16x8*)&cA[(wm + mb * 16 + l16) * 64 + ((ks * 4 + quad) ^ sw) * 8];
#pragma unroll
      for (int nb = 0; nb < 4; ++nb)
        bf[nb] = *(const f16x8*)&cB[(wn + nb * 16 + l16) * 64 + ((ks * 4 + quad) ^ sw) * 8];
      __builtin_amdgcn_s_setprio(1);
#pragma unroll
      for (int mb = 0; mb < 4; ++mb)
#pragma unroll
        for (int nb = 0; nb < 4; ++nb)
          acc[mb][nb] = mfma16(af[mb], bf[nb], acc[mb][nb]);
      __builtin_amdgcn_s_setprio(0);
    }
    asm volatile("s_waitcnt vmcnt(0)" ::: "memory");
    __builtin_amdgcn_s_barrier();
  }

#pragma unroll
  for (int nb = 0; nb < 4; ++nb) {
    int col = blockN + wn + nb * 16 + l16;
    float bv = bias[col];
#pragma unroll
    for (int mb = 0; mb < 4; ++mb) {
#pragma unroll
      for (int r = 0; r < 4; ++r) {
        int row = blockM + wm + mb * 16 + quad * 4 + r;
        out[(long)row * 1024 + col] = acc[mb][nb][r] + bv;
      }
    }
  }
}

extern "C" void kernel_launch(void* const* d_in, const int* in_sizes, int n_in,
                              void* d_out, int out_size, void* d_ws, size_t ws_size,
                              hipStream_t stream) {
  const float* x     = (const float*)d_in[0];
  const float* w_qkv = (const float*)d_in[1];
  const float* b_qkv = (const float*)d_in[2];
  const float* w_out = (const float*)d_in[3];
  const float* b_out = (const float*)d_in[4];
  float* out = (float*)d_out;

  char* ws = (char*)d_ws;
  f16* xh    = (f16*)(ws);                        // 16,777,216  [8192][1024]
  f16* ctx   = (f16*)(ws);                        // aliased (xh dead after qkv_gemm)
  f16* wqkvT = (f16*)(ws + 16777216);             //  6,291,456  [3072][1024]
  f16* woutT = (f16*)(ws + 23068672);             //  2,097,152  [1024][1024]
  f16* Qs    = (f16*)(ws + 25165824);             // 16,777,216  [64][2048][64] scaled
  f16* Kk    = (f16*)(ws + 41943040);             // 16,777,216  [64][2048][64]
  f16* Vt    = (f16*)(ws + 58720256);             // 16,777,216  [64][64][2048]

  prep<<<8192, 256, 0, stream>>>(x, xh, w_qkv, wqkvT, w_out, woutT);
  qkv_gemm<<<dim3(64, 24), 256, 0, stream>>>(xh, wqkvT, b_qkv, Qs, Kk, Vt);
  attn<<<dim3(8, 64), 512, 0, stream>>>(Qs, Kk, Vt, ctx);
  proj_gemm<<<dim3(64, 8), 256, 0, stream>>>(ctx, woutT, b_out, out);
}

// Round 9
// 244.002 us; speedup vs baseline: 1.1439x; 1.0410x over previous
//
#include <hip/hip_runtime.h>

// MultiheadAttention: B=4,S=2048,C=1024,E=1024,H=16,D=64. fp32 in/out.
// Pipeline: prep (cvt x->f16 + transpose w_qkv,w_out); QKV GEMM (f16 MFMA,
// fp32 acc) -> Q(scaled)/K [B,H,S,D], V^T [B,H,D,S]; flash attention ->
// ctx [tok][E]; out-proj GEMM -> fp32 d_out. 72MB workspace.
//
// R7: attn: full-rate 16x16x32 PV via key-permutation trick.
// R8: attn: permuted-key lV; XCD swizzle (bh per XCD, K/V L2-hot).
// R9: GEMMs: XCD swizzle (A-slice per XCD); BK=64 + XOR-swizzled LDS.
// R12: GEMMs: LDS dbuf + early-issue staging.
// R13/R14: attn conflict-free XOR LDS (8.4M->0) but gload_lds-K + early vmcnt
// cost 4us vs R12's reg-stage/late-write schedule (conflicts weren't critical).
// MfmaUtil+VALUBusy ~87% -> attn near issue-bound; residue = barrier overhead.
// R15: (a) attn: back to reg-stage EARLY-LOAD/LATE-WRITE (R12 schedule), keep
// stride-64 XOR layout (conflicts 0); (b) attn KVBLK=128: 2 K-tiles/iter ->
// halves barriers (32->16); LDS 64KB, still 2 blocks/CU; (c) qkv/proj: 512-thr
// blocks on 128^2 tile (8 waves of 32x64) -> occupancy cap 25%->50% to hide
// the vmcnt(0) drain.

typedef _Float16 f16;
typedef f16 f16x2 __attribute__((ext_vector_type(2)));
typedef f16 f16x4 __attribute__((ext_vector_type(4)));
typedef f16 f16x8 __attribute__((ext_vector_type(8)));
typedef float f32x4 __attribute__((ext_vector_type(4)));

typedef const __attribute__((address_space(1))) void* gas_ptr;
typedef __attribute__((address_space(3))) void* lds_ptr;

__device__ __forceinline__ void load_lds16(const void* g, void* s) {
  __builtin_amdgcn_global_load_lds((gas_ptr)g, (lds_ptr)s, 16, 0, 0);
}

__device__ __forceinline__ f32x4 mfma16(f16x8 a, f16x8 b, f32x4 c) {
  return __builtin_amdgcn_mfma_f32_16x16x32_f16(a, b, c, 0, 0, 0);
}

__device__ __forceinline__ f16x2 pk2(float a, float b) {
  return __builtin_bit_cast(f16x2, __builtin_amdgcn_cvt_pkrtz(a, b));
}

// ---------------- prep: cvt_x + tconv(w_qkv) + tconv(w_out), fused ----------------
// grid 8192 x 256thr: [0,4096) cvt; [4096,7168) wqkv T; [7168,8192) wout T.
__global__ __launch_bounds__(256) void prep(const float* __restrict__ x, f16* __restrict__ xh,
                                            const float* __restrict__ w_qkv, f16* __restrict__ wqkvT,
                                            const float* __restrict__ w_out, f16* __restrict__ woutT) {
  __shared__ float t[32][33];
  int bid = blockIdx.x, tid = threadIdx.x;
  if (bid < 4096) {
    long i = (long)bid * 256 + tid;
    const float4* p = (const float4*)x;
    float4 a = p[2 * i], b = p[2 * i + 1];
    f16x8 o;
    o[0] = (f16)a.x; o[1] = (f16)a.y; o[2] = (f16)a.z; o[3] = (f16)a.w;
    o[4] = (f16)b.x; o[5] = (f16)b.y; o[6] = (f16)b.z; o[7] = (f16)b.w;
    *(f16x8*)(xh + 8 * i) = o;
    return;
  }
  const float* in;
  f16* out;
  int R, C, c0, r0;
  if (bid < 7168) {
    int r = bid - 4096;                       // wqkv: in[1024][3072] -> out[3072][1024]
    in = w_qkv; out = wqkvT; R = 1024; C = 3072;
    c0 = (r % 96) * 32; r0 = (r / 96) * 32;
  } else {
    int r = bid - 7168;                       // wout: in[1024][1024] -> out[1024][1024]
    in = w_out; out = woutT; R = 1024; C = 1024;
    c0 = (r & 31) * 32; r0 = (r >> 5) * 32;
  }
  int tx = tid & 31, ty = tid >> 5;
#pragma unroll
  for (int j = 0; j < 4; ++j)
    t[ty + 8 * j][tx] = in[(long)(r0 + ty + 8 * j) * C + c0 + tx];
  __syncthreads();
#pragma unroll
  for (int j = 0; j < 4; ++j)
    out[(long)(c0 + ty + 8 * j) * R + r0 + tx] = (f16)t[tx][ty + 8 * j];
}

// ---------------- QKV GEMM (R15): [8192x1024] @ [1024x3072] + b ----------------
// 128x128 tile, 512 threads (8 waves of 32x64), BK=64, LDS dbuf + early-issue
// staging. grid (64,24).
__global__ __launch_bounds__(512, 4) void qkv_gemm(const f16* __restrict__ A, const f16* __restrict__ BT,
                                                   const float* __restrict__ bias,
                                                   f16* __restrict__ Qs, f16* __restrict__ Kk,
                                                   f16* __restrict__ Vt) {
  __shared__ __align__(16) f16 lA[2][128 * 64];
  __shared__ __align__(16) f16 lB[2][128 * 64];
  const int K = 1024;
  int tid = threadIdx.x, w = tid >> 6, lane = tid & 63, l16 = lane & 15, quad = lane >> 4;
  int wm = (w >> 1) * 32, wn = (w & 1) * 64;
  // XCD swizzle: XCD x owns blockM rows [8x,8x+8) (A slice 2MB, L2-resident).
  int id = blockIdx.y * gridDim.x + blockIdx.x;        // 1536 blocks
  int xcd = id & 7, cch = id >> 3;                     // cch in [0,192)
  int bx = xcd * 8 + (cch & 7), by = cch >> 3;         // by in [0,24)
  int blockM = bx * 128, blockN = by * 128;
  int sw = l16 & 7;
  f32x4 acc[2][4] = {};

  // stage K-tile kt into buffer kt&1: physical 16B-chunk pc of row r holds
  // global chunk pc^(r&7) (T2, rule 21): dest linear, source pre-swizzled.
  auto stage = [&](int kt) {
    int k0 = kt * 64;
    f16* dA = lA[kt & 1];
    f16* dB = lB[kt & 1];
#pragma unroll
    for (int i = 0; i < 2; ++i) {
      int c = i * 512 + tid;                 // chunk id: row = c>>3, col-chunk = c&7
      int row = c >> 3;
      int sc = (c & 7) ^ (row & 7);
      load_lds16(A + (long)(blockM + row) * K + k0 + sc * 8, dA + c * 8);
      load_lds16(BT + (long)(blockN + row) * K + k0 + sc * 8, dB + c * 8);
    }
  };

  stage(0);
  asm volatile("s_waitcnt vmcnt(0)" ::: "memory");
  __builtin_amdgcn_s_barrier();

  for (int t = 0; t < 16; ++t) {
    if (t < 15) stage(t + 1);                // latency overlaps compute below
    const f16* cA = lA[t & 1];
    const f16* cB = lB[t & 1];
#pragma unroll
    for (int ks = 0; ks < 2; ++ks) {
      f16x8 af[2], bf[4];
#pragma unroll
      for (int mb = 0; mb < 2; ++mb)
        af[mb] = *(const f16x8*)&cA[(wm + mb * 16 + l16) * 64 + ((ks * 4 + quad) ^ sw) * 8];
#pragma unroll
      for (int nb = 0; nb < 4; ++nb)
        bf[nb] = *(const f16x8*)&cB[(wn + nb * 16 + l16) * 64 + ((ks * 4 + quad) ^ sw) * 8];
      __builtin_amdgcn_s_setprio(1);
#pragma unroll
      for (int mb = 0; mb < 2; ++mb)
#pragma unroll
        for (int nb = 0; nb < 4; ++nb)
          acc[mb][nb] = mfma16(af[mb], bf[nb], acc[mb][nb]);
      __builtin_amdgcn_s_setprio(0);
    }
    asm volatile("s_waitcnt vmcnt(0)" ::: "memory");
    __builtin_amdgcn_s_barrier();
  }

  int which = by >> 3;                           // 0=Q,1=K,2=V (block-uniform)
  const float SCALE = 0.18033688011112042f;      // log2(e)/sqrt(D)
#pragma unroll
  for (int nb = 0; nb < 4; ++nb) {
    int col = blockN + wn + nb * 16 + l16;
    int hd = col & 1023, h = hd >> 6, d = hd & 63;
    float bv = bias[col];
#pragma unroll
    for (int mb = 0; mb < 2; ++mb) {
      int row0 = blockM + wm + mb * 16 + quad * 4;   // 4 consecutive tokens
      int b = row0 >> 11, s0 = row0 & 2047;
      if (which == 2) {
        f16x2 a = pk2(acc[mb][nb][0] + bv, acc[mb][nb][1] + bv);
        f16x2 c = pk2(acc[mb][nb][2] + bv, acc[mb][nb][3] + bv);
        *(f16x4*)&Vt[((b * 16 + h) * 64 + d) * 2048 + s0] =
            __builtin_shufflevector(a, c, 0, 1, 2, 3);
      } else if (which == 0) {
#pragma unroll
        for (int r = 0; r < 4; ++r)
          Qs[((b * 16 + h) * 2048 + s0 + r) * 64 + d] = (f16)((acc[mb][nb][r] + bv) * SCALE);
      } else {
#pragma unroll
        for (int r = 0; r < 4; ++r)
          Kk[((b * 16 + h) * 2048 + s0 + r) * 64 + d] = (f16)(acc[mb][nb][r] + bv);
      }
    }
  }
}

// ---------------- Flash attention (R15) ----------------
// grid (8,64) XCD-swizzled: XCD x owns bh in [8x,8x+8) (K/V L2-hot).
// 512 threads = 8 waves; wave owns 32 Q rows. KVBLK=128 (2 K-tiles/iter ->
// 16 barriers). Reg-stage EARLY-LOAD/LATE-WRITE (R12 schedule): loads issued
// at loop top overlap compute; ds_writes after compute; register deps order.
// LDS stride-64(K)/128(V) with 16B-chunk XOR swizzle c^=(row&7) both sides
// (conflicts 0). S^T=K*Q^T; P in regs; PV full-rate via key permutation;
// row-sum via ones-B MFMA. Q pre-scaled -> exp2 domain; no online max.
__global__ __launch_bounds__(512, 4) void attn(const f16* __restrict__ Qs, const f16* __restrict__ Kk,
                                               const f16* __restrict__ Vt, f16* __restrict__ ctx) {
  __shared__ __align__(16) f16 lK[2][128 * 64];  // [key][d], chunk-XOR
  __shared__ __align__(16) f16 lV[2][64 * 128];  // [d][perm key], chunk-XOR
  int id = blockIdx.y * gridDim.x + blockIdx.x;        // 512 blocks
  int swz = (id & 7) * 64 + (id >> 3);
  int qt = swz & 7, bh = swz >> 3;                     // XCD id&7 -> bh block
  int tid = threadIdx.x, lane = tid & 63, l16 = lane & 15, quad = lane >> 4;
  int w = tid >> 6;                               // 8 waves
  int swr = l16 & 7;
  const f16* Qbase = Qs + ((long)bh * 2048 + qt * 256 + w * 32) * 64;
  const f16* Kbh = Kk + (long)bh * 2048 * 64;
  const f16* Vbh = Vt + (long)bh * 64 * 2048;

  f16x8 qf[2][2];                                // B-frag: [n=row=rb*16+l16][k=d]
#pragma unroll
  for (int rb = 0; rb < 2; ++rb)
#pragma unroll
    for (int ks = 0; ks < 2; ++ks)
      qf[rb][ks] = *(const f16x8*)(Qbase + (rb * 16 + l16) * 64 + ks * 32 + quad * 8);

  f32x4 of[2][4] = {};
  f32x4 osum[2] = {};
  const f16 one = (f16)1.f;
  const f16x8 vone8 = {one, one, one, one, one, one, one, one};

  // K staging: thread covers rows rk0, rk0+64 (chunk cl each); both rows share
  // rk&7 -> same XOR. V staging: rows dv0, dv0+32, 16 chunks each.
  int rk0 = tid >> 3, cl = tid & 7;
  int jjk = rk0 & 7;
  int kCl = (cl ^ jjk) * 8;
  int dv0 = tid >> 4, ck = tid & 15, o = ck * 8;
  int jjv = dv0 & 7;                              // == (dv0+32)&7
  // lV logical perm (R8): key g*32+16h+4qa+j -> col g*32+8qa+4h+j.
  int koff = o & 31;
  int Lp = (o & 96) + ((koff & 12) << 1) + ((koff >> 4) << 2);
  // physical byte of logical 4-group L in row r: (((L>>3)^(r&7))<<4)+((L&4)<<1)
  int pv0b = (((Lp >> 3) ^ jjv) << 4) + ((Lp & 4) << 1);
  int pv1b = ((((Lp >> 3) + 1) ^ jjv) << 4) + ((Lp & 4) << 1);

  auto loadKV = [&](int kt, float4& ka, float4& kb_, float4& va, float4& vb) {
    int kb0 = kt * 128;
    ka  = *(const float4*)(Kbh + (kb0 + rk0) * 64 + cl * 8);
    kb_ = *(const float4*)(Kbh + (kb0 + rk0 + 64) * 64 + cl * 8);
    va  = *(const float4*)(Vbh + (long)dv0 * 2048 + kb0 + o);
    vb  = *(const float4*)(Vbh + (long)(dv0 + 32) * 2048 + kb0 + o);
  };
  auto writeKV = [&](int buf, float4 ka, float4 kb_, float4 va, float4 vb) {
    *(f16x8*)&lK[buf][rk0 * 64 + kCl] = __builtin_bit_cast(f16x8, ka);
    *(f16x8*)&lK[buf][(rk0 + 64) * 64 + kCl] = __builtin_bit_cast(f16x8, kb_);
    char* d0 = (char*)(lV[buf] + dv0 * 128);
    char* d1 = (char*)(lV[buf] + (dv0 + 32) * 128);
    f16x8 a8 = __builtin_bit_cast(f16x8, va);
    f16x8 b8 = __builtin_bit_cast(f16x8, vb);
    *(f16x4*)(d0 + pv0b) = __builtin_shufflevector(a8, a8, 0, 1, 2, 3);
    *(f16x4*)(d0 + pv1b) = __builtin_shufflevector(a8, a8, 4, 5, 6, 7);
    *(f16x4*)(d1 + pv0b) = __builtin_shufflevector(b8, b8, 0, 1, 2, 3);
    *(f16x4*)(d1 + pv1b) = __builtin_shufflevector(b8, b8, 4, 5, 6, 7);
  };

  // preload tile 0
  {
    float4 ka, kb_, va, vb;
    loadKV(0, ka, kb_, va, vb);
    writeKV(0, ka, kb_, va, vb);
  }
  __syncthreads();

  for (int kt = 0; kt < 16; ++kt) {
    int cur = kt & 1, nxt = cur ^ 1;

    // issue next tile's loads first: latency overlaps compute below.
    float4 ka, kb_, va, vb;
    if (kt < 15) loadKV(kt + 1, ka, kb_, va, vb);

    __builtin_amdgcn_s_setprio(1);
#pragma unroll
    for (int kp = 0; kp < 4; ++kp) {             // 32-key group
      f16x4 pah[2][2];                           // [rb][kbh]: packed exp, keys 4q..4q+3
#pragma unroll
      for (int kbh = 0; kbh < 2; ++kbh) {
        int kb = kp * 2 + kbh;
        f16x8 kf0 = *(const f16x8*)&lK[cur][(kb * 16 + l16) * 64 + ((quad ^ swr) << 3)];
        f16x8 kf1 = *(const f16x8*)&lK[cur][(kb * 16 + l16) * 64 + (((4 + quad) ^ swr) << 3)];
#pragma unroll
        for (int rb = 0; rb < 2; ++rb) {
          f32x4 z = {};
          z = mfma16(kf0, qf[rb][0], z);
          z = mfma16(kf1, qf[rb][1], z);
          float p0 = __builtin_amdgcn_exp2f(z[0]);
          float p1 = __builtin_amdgcn_exp2f(z[1]);
          float p2 = __builtin_amdgcn_exp2f(z[2]);
          float p3 = __builtin_amdgcn_exp2f(z[3]);
          pah[rb][kbh] = __builtin_shufflevector(pk2(p0, p1), pk2(p2, p3), 0, 1, 2, 3);
        }
      }
      // A-frag (16x16x32): slot (quad,j) holds permuted key set; k-sum invariant
      f16x8 pa[2];
      pa[0] = __builtin_shufflevector(pah[0][0], pah[0][1], 0, 1, 2, 3, 4, 5, 6, 7);
      pa[1] = __builtin_shufflevector(pah[1][0], pah[1][1], 0, 1, 2, 3, 4, 5, 6, 7);

      // O += P V (full-rate); V key-permuted -> one b128 per db
#pragma unroll
      for (int db = 0; db < 4; ++db) {
        f16x8 vf = *(const f16x8*)&lV[cur][(db * 16 + l16) * 128 + (((kp * 4 + quad) ^ swr) << 3)];
#pragma unroll
        for (int rb = 0; rb < 2; ++rb)
          of[rb][db] = mfma16(pa[rb], vf, of[rb][db]);
      }
#pragma unroll
      for (int rb = 0; rb < 2; ++rb)
        osum[rb] = mfma16(pa[rb], vone8, osum[rb]);
    }
    __builtin_amdgcn_s_setprio(0);

    // commit prefetch to the other buffer; single barrier per iteration
    if (kt < 15) {
      writeKV(nxt, ka, kb_, va, vb);
      __syncthreads();
    }
  }

  int b = bh >> 4, h = bh & 15;
  long token0 = (long)b * 2048 + qt * 256 + w * 32;
#pragma unroll
  for (int rb = 0; rb < 2; ++rb) {
    float inv[4];
#pragma unroll
    for (int r = 0; r < 4; ++r) inv[r] = 1.0f / osum[rb][r];   // in-lane: same C-layout
#pragma unroll
    for (int db = 0; db < 4; ++db)
#pragma unroll
      for (int r = 0; r < 4; ++r)
        ctx[(token0 + rb * 16 + quad * 4 + r) * 1024 + h * 64 + db * 16 + l16] =
            (f16)(of[rb][db][r] * inv[r]);
  }
}

// ---------------- out-proj GEMM (R15): [8192x1024] @ [1024x1024] + b -> fp32 ----------------
// 128x128 tile, 512 threads (8 waves of 32x64), BK=64, dbuf + early-issue.
__global__ __launch_bounds__(512, 4) void proj_gemm(const f16* __restrict__ A, const f16* __restrict__ BT,
                                                    const float* __restrict__ bias,
                                                    float* __restrict__ out) {
  __shared__ __align__(16) f16 lA[2][128 * 64];
  __shared__ __align__(16) f16 lB[2][128 * 64];
  const int K = 1024;
  int tid = threadIdx.x, w = tid >> 6, lane = tid & 63, l16 = lane & 15, quad = lane >> 4;
  int wm = (w >> 1) * 32, wn = (w & 1) * 64;
  int id = blockIdx.y * gridDim.x + blockIdx.x;        // 512 blocks
  int xcd = id & 7, cch = id >> 3;                     // cch in [0,64)
  int bx = xcd * 8 + (cch & 7), by = cch >> 3;         // by in [0,8)
  int blockM = bx * 128, blockN = by * 128;
  int sw = l16 & 7;
  f32x4 acc[2][4] = {};

  auto stage = [&](int kt) {
    int k0 = kt * 64;
    f16* dA = lA[kt & 1];
    f16* dB = lB[kt & 1];
#pragma unroll
    for (int i = 0; i < 2; ++i) {
      int c = i * 512 + tid;
      int row = c >> 3;
      int sc = (c & 7) ^ (row & 7);
      load_lds16(A + (long)(blockM + row) * K + k0 + sc * 8, dA + c * 8);
      load_lds16(BT + (long)(blockN + row) * K + k0 + sc * 8, dB + c * 8);
    }
  };

  stage(0);
  asm volatile("s_waitcnt vmcnt(0)" ::: "memory");
  __builtin_amdgcn_s_barrier();

  for (int t = 0; t < 16; ++t) {
    if (t < 15) stage(t + 1);
    const f16* cA = lA[t & 1];
    const f16* cB = lB[t & 1];
#pragma unroll
    for (int ks = 0; ks < 2; ++ks) {
      f16x8 af[2], bf[4];
#pragma unroll
      for (int mb = 0; mb < 2; ++mb)
        af[mb] = *(const f16x8*)&cA[(wm + mb * 16 + l16) * 64 + ((ks * 4 + quad) ^ sw) * 8];
#pragma unroll
      for (int nb = 0; nb < 4; ++nb)
        bf[nb] = *(const f16x8*)&cB[(wn + nb * 16 + l16) * 64 + ((ks * 4 + quad) ^ sw) * 8];
      __builtin_amdgcn_s_setprio(1);
#pragma unroll
      for (int mb = 0; mb < 2; ++mb)
#pragma unroll
        for (int nb = 0; nb < 4; ++nb)
          acc[mb][nb] = mfma16(af[mb], bf[nb], acc[mb][nb]);
      __builtin_amdgcn_s_setprio(0);
    }
    asm volatile("s_waitcnt vmcnt(0)" ::: "memory");
    __builtin_amdgcn_s_barrier();
  }

#pragma unroll
  for (int nb = 0; nb < 4; ++nb) {
    int col = blockN + wn + nb * 16 + l16;
    float bv = bias[col];
#pragma unroll
    for (int mb = 0; mb < 2; ++mb) {
#pragma unroll
      for (int r = 0; r < 4; ++r) {
        int row = blockM + wm + mb * 16 + quad * 4 + r;
        out[(long)row * 1024 + col] = acc[mb][nb][r] + bv;
      }
    }
  }
}

extern "C" void kernel_launch(void* const* d_in, const int* in_sizes, int n_in,
                              void* d_out, int out_size, void* d_ws, size_t ws_size,
                              hipStream_t stream) {
  const float* x     = (const float*)d_in[0];
  const float* w_qkv = (const float*)d_in[1];
  const float* b_qkv = (const float*)d_in[2];
  const float* w_out = (const float*)d_in[3];
  const float* b_out = (const float*)d_in[4];
  float* out = (float*)d_out;

  char* ws = (char*)d_ws;
  f16* xh    = (f16*)(ws);                        // 16,777,216  [8192][1024]
  f16* ctx   = (f16*)(ws);                        // aliased (xh dead after qkv_gemm)
  f16* wqkvT = (f16*)(ws + 16777216);             //  6,291,456  [3072][1024]
  f16* woutT = (f16*)(ws + 23068672);             //  2,097,152  [1024][1024]
  f16* Qs    = (f16*)(ws + 25165824);             // 16,777,216  [64][2048][64] scaled
  f16* Kk    = (f16*)(ws + 41943040);             // 16,777,216  [64][2048][64]
  f16* Vt    = (f16*)(ws + 58720256);             // 16,777,216  [64][64][2048]

  prep<<<8192, 256, 0, stream>>>(x, xh, w_qkv, wqkvT, w_out, woutT);
  qkv_gemm<<<dim3(64, 24), 512, 0, stream>>>(xh, wqkvT, b_qkv, Qs, Kk, Vt);
  attn<<<dim3(8, 64), 512, 0, stream>>>(Qs, Kk, Vt, ctx);
  proj_gemm<<<dim3(64, 8), 512, 0, stream>>>(ctx, woutT, b_out, out);
}